// Round 8
// baseline (6457.353 us; speedup 1.0000x reference)
//
#include <hip/hip_runtime.h>

typedef unsigned short u16;
typedef unsigned int u32;
typedef __bf16 bf16x8 __attribute__((ext_vector_type(8)));
typedef float f32x4 __attribute__((ext_vector_type(4)));

#define NB 16
#define CIN 26
#define IMH 96
#define IMW 72
#define HW6912 6912      // 96*72
#define NPIX 110592      // 16*6912
// small padded geom (all internal activations): 98 x 74, pad 1
#define SPH 98
#define SPW 74
#define SPAD 1

__device__ __forceinline__ float b2f(u16 h) {
    union { u32 u; float f; } x; x.u = ((u32)h) << 16; return x.f;
}
__device__ __forceinline__ u16 f2b(float f) {
    union { float f; u32 u; } x; x.f = f;
    u32 u = x.u;
    u32 r = (u + 0x7fffu + ((u >> 16) & 1u)) >> 16;
    return (u16)r;
}
__device__ __forceinline__ float ldin(const void* p, int i, int f) {
    return f ? ((const float*)p)[i] : b2f(((const u16*)p)[i]);
}

// map flat pixel m -> element offset in small padded NHWC buffer, (1<<clog2) ch
__device__ __forceinline__ int pbase(int m, int clog2) {
    int b = m / HW6912;
    int p = m - b * HW6912;
    int y = p / IMW;
    int x = p - y * IMW;
    return (((b * SPH + y + SPAD) * SPW) + (x + SPAD)) << clog2;
}

__device__ __forceinline__ void glds16(const u16* g, u16* l) {
    __builtin_amdgcn_global_load_lds(
        (const __attribute__((address_space(1))) void*)g,
        (__attribute__((address_space(3))) void*)l, 16, 0, 0);
}

// ---------------------------------------------------------------- dtype probe
__global__ void probe_kernel(const void* bn, int* flag) {
    if (threadIdx.x == 0 && blockIdx.x == 0) {
        const float* f = (const float*)bn;
        int cnt = 0;
        for (int j = 64; j < 128; ++j) {
            float v = f[j];
            if (v >= 0.4f && v <= 1.6f) cnt++;
        }
        *flag = (cnt >= 32) ? 1 : 0;
    }
}

// ---------------------------------------------------------------- zero
__global__ __launch_bounds__(256) void zero_ws_kernel(uint4* p, int n16) {
    int i = blockIdx.x * 256 + threadIdx.x;
    int stride = gridDim.x * 256;
    for (; i < n16; i += stride) p[i] = make_uint4(0u, 0u, 0u, 0u);
}

// ---------------------------------------------------------------- x0 = ref - sup -> small padded NHWC(32)
__global__ __launch_bounds__(256) void fill_x0_kernel(const void* __restrict__ ref,
                                                      const void* __restrict__ sup,
                                                      u16* __restrict__ x0,
                                                      const int* __restrict__ flag) {
    int f = *flag;
    int t = blockIdx.x * 256 + threadIdx.x;
    int b = t / HW6912;
    int p = t - b * HW6912;
    int y = p / IMW;
    int x = p - y * IMW;
    int dst = ((b * SPH + y + SPAD) * SPW + (x + SPAD)) << 5;
    #pragma unroll 1
    for (int c = 0; c < CIN; ++c) {
        int src = (b * CIN + c) * HW6912 + p;
        x0[dst + c] = f2b(ldin(ref, src, f) - ldin(sup, src, f));
    }
}

// ---------------------------------------------------------------- weight preps
// prep_rest v2: chain weights in MFMA-fragment order (same transform as
// prep_off v2, harness-verified):
//   layer c, elem e = (((nt*36+it)*2+w2)*2+j)*512 + l*8 + ee
//   n = nt*64 + w2*32 + j*16 + (l&15); k = it*32 + (l>>4)*8 + ee
__global__ __launch_bounds__(256) void prep_rest_kernel(const void* __restrict__ w1r,
                                                        const void* __restrict__ w2r,
                                                        const void* __restrict__ bn1r,
                                                        const void* __restrict__ bn2r,
                                                        u16* __restrict__ dst,
                                                        const int* __restrict__ flag) {
    int f = *flag;
    int idx = blockIdx.x * 256 + threadIdx.x;        // 38*147456
    int c = idx / 147456;
    int e = idx - c * 147456;
    int ee = e & 7;
    int l = (e >> 3) & 63;
    int j = (e >> 9) & 1;
    int w2 = (e >> 10) & 1;
    int rest = e >> 11;            // 0..71
    int it = rest % 36;
    int nt = rest / 36;
    int n = nt * 64 + w2 * 32 + j * 16 + (l & 15);
    int k = it * 32 + ((l >> 4) << 3) + ee;
    int s = k >> 7, ci = k & 127;
    const void* w  = (c < 19) ? w1r : w2r;
    int wb         = ((c < 19) ? c : (c - 19)) * 147456;
    const void* bn = (c < 19) ? bn1r : bn2r;
    int bb         = ((c < 19) ? c : (c - 19)) * 512;
    float inv = ldin(bn, bb + n, f) * rsqrtf(ldin(bn, bb + 384 + n, f) + 1e-5f);
    dst[idx] = f2b(ldin(w, wb + (n * 128 + ci) * 9 + s, f) * inv);
}

__global__ __launch_bounds__(256) void prep_b0_kernel(const void* __restrict__ w1_0,
                                                      const void* __restrict__ w2_0,
                                                      const void* __restrict__ wd_0,
                                                      const void* __restrict__ bn1_0,
                                                      const void* __restrict__ bn2_0,
                                                      const void* __restrict__ bnd_0,
                                                      u16* __restrict__ W20,
                                                      u16* __restrict__ W10,
                                                      u16* __restrict__ Wd,
                                                      const int* __restrict__ flag) {
    int f = *flag;
    int idx = blockIdx.x * 256 + threadIdx.x;  // 188416
    if (idx < 147456) {
        // W20 in fragment order (for chain_conv)
        int e = idx;
        int ee = e & 7;
        int l = (e >> 3) & 63;
        int j = (e >> 9) & 1;
        int w2 = (e >> 10) & 1;
        int rest = e >> 11;
        int it = rest % 36;
        int nt = rest / 36;
        int n = nt * 64 + w2 * 32 + j * 16 + (l & 15);
        int k = it * 32 + ((l >> 4) << 3) + ee;
        int s = k >> 7, ci = k & 127;
        float inv = ldin(bn2_0, n, f) * rsqrtf(ldin(bn2_0, 384 + n, f) + 1e-5f);
        W20[idx] = f2b(ldin(w2_0, (n * 128 + ci) * 9 + s, f) * inv);
    } else if (idx < 184320) {
        int j = idx - 147456;
        int o = j / 288, k = j - o * 288;
        int s = k >> 5, ci = k & 31;
        float inv = ldin(bn1_0, o, f) * rsqrtf(ldin(bn1_0, 384 + o, f) + 1e-5f);
        W10[j] = (ci < CIN) ? f2b(ldin(w1_0, (o * CIN + ci) * 9 + s, f) * inv) : (u16)0;
    } else {
        int j = idx - 184320;
        int o = j >> 5, ci = j & 31;
        float inv = ldin(bnd_0, o, f) * rsqrtf(ldin(bnd_0, 384 + o, f) + 1e-5f);
        Wd[j] = (ci < CIN) ? f2b(ldin(wd_0, o * CIN + ci, f) * inv) : (u16)0;
    }
}

// prep_off v2: store W in MFMA-fragment order so off_conv can load B direct
// to VGPR fully coalesced (16 B/lane):
//   dst elem = ((((d*8+nt)*36+it)*2+w2)*2+j)*512 + lane*8 + e
//   where n = nt*64 + w2*32 + j*16 + (lane&15), k = it*32 + (lane>>4)*8 + e
__global__ __launch_bounds__(256) void prep_off_kernel(const void* __restrict__ offw,
                                                       u16* __restrict__ dst,
                                                       const int* __restrict__ flag) {
    int f = *flag;
    int idx = blockIdx.x * 256 + threadIdx.x;    // 5*8*36*2*2*512 = 2,949,120
    int e = idx & 7;
    int l = (idx >> 3) & 63;
    int j = (idx >> 9) & 1;
    int w2 = (idx >> 10) & 1;
    int rest = idx >> 11;
    int it = rest % 36;
    int dnt = rest / 36;
    int nt = dnt & 7;
    int d = dnt >> 3;
    int n = nt * 64 + w2 * 32 + j * 16 + (l & 15);
    int k = it * 32 + (l >> 4) * 8 + e;
    int s = k >> 7, ci = k & 127;
    dst[idx] = (n < 468) ? f2b(ldin(offw, ((d * 468 + n) * 128 + ci) * 9 + s, f)) : (u16)0;
}

// prep_dw: deform weights -> [5][26ch c][9 tap][28 o-padded] float, so
// deform_kernel stages wsm with coalesced float4 loads instead of 6552
// scattered scalar loads per block (that per-block tax is what made the
// R7 32px split regress).
__global__ __launch_bounds__(256) void prep_dw_kernel(const void* __restrict__ dwall,
                                                      float* __restrict__ dst,
                                                      const int* __restrict__ flag) {
    int f = *flag;
    int idx = blockIdx.x * 256 + threadIdx.x;    // 5*6552 = 32760
    if (idx >= 32760) return;
    int d = idx / 6552;
    int r = idx - d * 6552;
    int o = r % 28;
    int ct = r / 28;
    int c = ct / 9, t = ct - c * 9;
    dst[idx] = (o < CIN) ? ldin(dwall, d * 6084 + (o * CIN + c) * 9 + t, f) : 0.f;
}

__global__ __launch_bounds__(256) void prep_bias_kernel(const void* __restrict__ bn1_0,
                                                        const void* __restrict__ bn2_0,
                                                        const void* __restrict__ bnd_0,
                                                        const void* __restrict__ bn1r,
                                                        const void* __restrict__ bn2r,
                                                        float* __restrict__ dst,
                                                        const int* __restrict__ flag) {
    int f = *flag;
    int idx = blockIdx.x * 256 + threadIdx.x;
    if (idx >= 41 * 128) return;
    int set = idx >> 7;
    int o = idx & 127;
    const void* bn; int bb = 0;
    if (set == 0) bn = bn1_0;
    else if (set == 1) bn = bn2_0;
    else if (set == 2) bn = bnd_0;
    else if (set < 22) { bn = bn1r; bb = (set - 3) * 512; }
    else { bn = bn2r; bb = (set - 22) * 512; }
    float s = ldin(bn, bb + o, f), b = ldin(bn, bb + 128 + o, f);
    float mu = ldin(bn, bb + 256 + o, f), v = ldin(bn, bb + 384 + o, f);
    float inv = s * rsqrtf(v + 1e-5f);
    dst[idx] = b - mu * inv;
}

// ---------------------------------------------------------------- generic implicit-GEMM conv (R7 structure)
// Used only for the two cheap x0 convs (K=32 / K=288). 128x64 tile, BK=32,
// ping-pong LDS via global_load_lds, one barrier/iter. out: small padded 128ch.
__global__ __launch_bounds__(256) void conv_gemm(const u16* __restrict__ A,
                                                 const u16* __restrict__ W,
                                                 const float* __restrict__ bias,
                                                 u16* __restrict__ out,
                                                 int clog2, int nslab, int K,
                                                 int relu) {
    __shared__ u16 As[2][128 * 32];
    __shared__ u16 Bs[2][64 * 32];
    int tid = threadIdx.x;
    int m0 = blockIdx.x * 128;
    int n0 = blockIdx.y * 64;
    int Cin = 1 << clog2;

    int r0 = tid >> 2;
    int q8 = (tid & 3) * 8;
    int arow0 = pbase(m0 + r0, clog2) + q8;
    int arow1 = pbase(m0 + r0 + 64, clog2) + q8;
    int brow0 = (n0 + r0) * K + q8;
    int l8 = tid * 8;

    f32x4 acc[4][2];
    #pragma unroll
    for (int i = 0; i < 4; ++i)
        #pragma unroll
        for (int j = 0; j < 2; ++j)
            acc[i][j] = (f32x4){0.f, 0.f, 0.f, 0.f};

    int wid = tid >> 6;
    int wm = (wid >> 1) * 64;
    int wn = (wid & 1) * 32;
    int lane = tid & 63;
    int lr = lane & 15;
    int lq = lane >> 4;

    int nk = K >> 5;
    auto stage = [&](int buf, int kt) {
        int sl = kt >> clog2;
        int win = kt & (Cin - 1);
        int soff = 0;
        if (nslab == 9) {
            int d3 = sl / 3;
            soff = (((d3 - 1) * SPW + (sl - d3 * 3 - 1))) << clog2;
        }
        glds16(A + arow0 + soff + win, &As[buf][l8]);
        glds16(A + arow1 + soff + win, &As[buf][2048 + l8]);
        glds16(W + brow0 + kt, &Bs[buf][l8]);
    };

    stage(0, 0);
    #pragma unroll 1
    for (int it = 0; it < nk; ++it) {
        __syncthreads();
        if (it + 1 < nk) stage((it + 1) & 1, (it + 1) << 5);
        const u16* as = As[it & 1];
        const u16* bs = Bs[it & 1];
        bf16x8 af[4], bfr[2];
        #pragma unroll
        for (int i = 0; i < 4; ++i)
            af[i] = *(const bf16x8*)&as[(wm + i * 16 + lr) * 32 + lq * 8];
        #pragma unroll
        for (int j = 0; j < 2; ++j)
            bfr[j] = *(const bf16x8*)&bs[(wn + j * 16 + lr) * 32 + lq * 8];
        #pragma unroll
        for (int i = 0; i < 4; ++i)
            #pragma unroll
            for (int j = 0; j < 2; ++j)
                acc[i][j] = __builtin_amdgcn_mfma_f32_16x16x32_bf16(af[i], bfr[j], acc[i][j], 0, 0, 0);
    }

    #pragma unroll
    for (int i = 0; i < 4; ++i) {
        #pragma unroll
        for (int r = 0; r < 4; ++r) {
            int ml = m0 + wm + i * 16 + lq * 4 + r;
            int ob = pbase(ml, 7);
            #pragma unroll
            for (int j = 0; j < 2; ++j) {
                int n = n0 + wn + j * 16 + lr;
                float v = acc[i][j][r] + bias[n];
                if (relu) v = fmaxf(v, 0.f);
                out[ob + n] = f2b(v);
            }
        }
    }
}

// ---------------------------------------------------------------- chain conv (dil=1, 128ch in, 128ch out, K=1152)
// v6: + XCD-locality swizzle (each XCD owns 108 contiguous mt = 2 images,
// both nt-tiles adjacent; FETCH 133MB -> expected ~40-55MB).
__global__ __launch_bounds__(256, 8) void chain_conv(const u16* __restrict__ A,
                                                     const u16* __restrict__ W,   // frag-ordered [2][36][2][2][512]
                                                     const float* __restrict__ bias,
                                                     const u16* __restrict__ idn,
                                                     u16* __restrict__ out,
                                                     int relu) {
    __shared__ u16 As[2][128 * 32];
    int tid = threadIdx.x;
    int wg = blockIdx.x;
    int sw = (wg & 7) * 216 + (wg >> 3);   // bijective: 1728 = 8*216
    int mt = sw >> 1, nt = sw & 1;
    int m0 = mt * 128, n0 = nt * 64;

    int r0 = tid >> 2;
    int q8 = (tid & 3) * 8;
    int pbq[2];
    #pragma unroll
    for (int q = 0; q < 2; ++q) {
        int p = m0 + r0 + q * 64;
        int b = p / HW6912;
        int rem = p - b * HW6912;
        int y = rem / IMW;
        int x = rem - y * IMW;
        pbq[q] = ((b * SPH + y + 1) * SPW + (x + 1)) * 128;
    }
    int l8 = tid * 8;

    f32x4 acc[4][2];
    #pragma unroll
    for (int i = 0; i < 4; ++i) {
        acc[i][0] = (f32x4){0.f, 0.f, 0.f, 0.f};
        acc[i][1] = (f32x4){0.f, 0.f, 0.f, 0.f};
    }

    int wid = tid >> 6;
    int wm = (wid >> 1) * 64;
    int w2 = wid & 1;
    int wn = w2 * 32;
    int lane = tid & 63;
    int lr = lane & 15;
    int lq = lane >> 4;

    // fragment-ordered W base for this wave: + it*2048 + j*512 per fragment
    const u16* wv = W + nt * 73728 + w2 * 1024 + lane * 8;

    auto stage = [&](int buf, int kt) {
        int sl = kt >> 7;           // tap 0..8
        int win = kt & 127;
        int d3 = sl / 3;
        int soff = ((d3 - 1) * SPW + (sl - d3 * 3 - 1)) * 128;
        glds16(A + pbq[0] + soff + win + q8, &As[buf][l8]);
        glds16(A + pbq[1] + soff + win + q8, &As[buf][2048 + l8]);
    };

    stage(0, 0);
    #pragma unroll 1
    for (int it = 0; it < 36; ++it) {
        __syncthreads();
        if (it + 1 < 36) stage((it + 1) & 1, (it + 1) << 5);
        const u16* as = As[it & 1];
        bf16x8 af[4], bfr[2];
        #pragma unroll
        for (int i = 0; i < 4; ++i)
            af[i] = *(const bf16x8*)&as[(wm + i * 16 + lr) * 32 + lq * 8];
        bfr[0] = *(const bf16x8*)(wv + it * 2048);
        bfr[1] = *(const bf16x8*)(wv + it * 2048 + 512);
        #pragma unroll
        for (int i = 0; i < 4; ++i)
            #pragma unroll
            for (int j = 0; j < 2; ++j)
                acc[i][j] = __builtin_amdgcn_mfma_f32_16x16x32_bf16(af[i], bfr[j], acc[i][j], 0, 0, 0);
    }

    #pragma unroll
    for (int i = 0; i < 4; ++i) {
        #pragma unroll
        for (int r = 0; r < 4; ++r) {
            int ml = m0 + wm + i * 16 + lq * 4 + r;
            int ob = pbase(ml, 7);
            #pragma unroll
            for (int j = 0; j < 2; ++j) {
                int n = n0 + wn + j * 16 + lr;
                float v = acc[i][j][r] + bias[n];
                if (idn) v += b2f(idn[ob + n]);
                if (relu) v = fmaxf(v, 0.f);
                out[ob + n] = f2b(v);
            }
        }
    }
}

// ---------------------------------------------------------------- offset conv (dilated, reads h1s with explicit zero-pad)
// v3: + XCD-locality swizzle: each XCD owns 27 consecutive mt with all 8
// nt-tiles of an mt adjacent in schedule.
__global__ __launch_bounds__(256, 8) void off_conv(const u16* __restrict__ A,   // h1s
                                                   const u16* __restrict__ W,   // frag-ordered [nt][it][w2][j][64*8]
                                                   u16* __restrict__ out,       // [m_local][468]
                                                   int dil, int m_base) {
    __shared__ u16 As[2][128 * 32];
    int tid = threadIdx.x;
    int wg = blockIdx.x;
    int sw = (wg & 7) * 216 + (wg >> 3);   // bijective: 1728 = 8*216
    int mt = sw >> 3, nt = sw & 7;
    int m0 = mt * 128, n0 = nt * 64;

    int r0 = tid >> 2;
    int q8 = (tid & 3) * 8;
    int pb2[2], py[2], px[2];
    #pragma unroll
    for (int q = 0; q < 2; ++q) {
        int p = m_base + m0 + r0 + q * 64;
        int b = p / HW6912;
        int rem = p - b * HW6912;
        pb2[q] = b;
        py[q] = rem / IMW;
        px[q] = rem - py[q] * IMW;
    }
    int l8 = tid * 8;

    f32x4 acc[4][2];
    #pragma unroll
    for (int i = 0; i < 4; ++i) {
        acc[i][0] = (f32x4){0.f, 0.f, 0.f, 0.f};
        acc[i][1] = (f32x4){0.f, 0.f, 0.f, 0.f};
    }

    int wid = tid >> 6;
    int wm = (wid >> 1) * 64;
    int wn = (wid & 1) * 32;
    int lane = tid & 63;
    int lr = lane & 15;
    int lq = lane >> 4;

    // fragment-ordered W base for this wave: + it*2048 + j*512 per fragment
    const u16* wv = W + nt * 73728 + (wid & 1) * 1024 + lane * 8;

    auto stage = [&](int buf, int kt) {
        int sl = kt >> 7;
        int win = kt & 127;
        int d3 = sl / 3;
        int dy = (d3 - 1) * dil, dx = (sl - d3 * 3 - 1) * dil;
        #pragma unroll
        for (int q = 0; q < 2; ++q) {
            int y2 = py[q] + dy, x2 = px[q] + dx;
            uint4 v = make_uint4(0u, 0u, 0u, 0u);
            if (y2 >= 0 && y2 < IMH && x2 >= 0 && x2 < IMW)
                v = *(const uint4*)(A + ((pb2[q] * SPH + y2 + 1) * SPW + x2 + 1) * 128 + win + q8);
            *(uint4*)&As[buf][q * 2048 + l8] = v;
        }
    };

    stage(0, 0);
    #pragma unroll 1
    for (int it = 0; it < 36; ++it) {
        __syncthreads();
        if (it + 1 < 36) stage((it + 1) & 1, (it + 1) << 5);
        const u16* as = As[it & 1];
        bf16x8 af[4], bfr[2];
        #pragma unroll
        for (int i = 0; i < 4; ++i)
            af[i] = *(const bf16x8*)&as[(wm + i * 16 + lr) * 32 + lq * 8];
        bfr[0] = *(const bf16x8*)(wv + it * 2048);
        bfr[1] = *(const bf16x8*)(wv + it * 2048 + 512);
        #pragma unroll
        for (int i = 0; i < 4; ++i)
            #pragma unroll
            for (int j = 0; j < 2; ++j)
                acc[i][j] = __builtin_amdgcn_mfma_f32_16x16x32_bf16(af[i], bfr[j], acc[i][j], 0, 0, 0);
    }

    #pragma unroll
    for (int i = 0; i < 4; ++i) {
        #pragma unroll
        for (int r = 0; r < 4; ++r) {
            int ml = m0 + wm + i * 16 + lq * 4 + r;
            int ob = ml * 468;
            #pragma unroll
            for (int j = 0; j < 2; ++j) {
                int n = n0 + wn + j * 16 + lr;
                if (n < 468) out[ob + n] = f2b(acc[i][j][r]);
            }
        }
    }
}

// ---------------------------------------------------------------- deformable conv
template <int F>
__device__ __forceinline__ float dsamp2(const void* sup, int base, int yi, int xi) {
    bool ok = (yi >= 0) & (yi < IMH) & (xi >= 0) & (xi < IMW);
    int yc = yi < 0 ? 0 : (yi > IMH - 1 ? IMH - 1 : yi);
    int xc = xi < 0 ? 0 : (xi > IMW - 1 ? IMW - 1 : xi);
    float v = F ? ((const float*)sup)[base + yc * IMW + xc]
                : b2f(((const u16*)sup)[base + yc * IMW + xc]);
    return ok ? v : 0.f;
}

template <int F>
__device__ __forceinline__ void deform_body(const void* __restrict__ sup,
                                            const u16* __restrict__ oc,
                                            const float* __restrict__ wsm,
                                            f32x4 acc[7],
                                            int c0, int c1, int b, int y, int x, int dil) {
    #pragma unroll 1
    for (int c = c0; c < c1; ++c) {
        int ibase = (b * CIN + c) * HW6912;
        #pragma unroll
        for (int t = 0; t < 9; ++t) {
            u32 pr = *(const u32*)(oc + c * 18 + t * 2);
            float dy = b2f((u16)(pr & 0xffffu));
            float dx = b2f((u16)(pr >> 16));
            float py = (float)(y + (t / 3 - 1) * dil) + dy;
            float px = (float)(x + (t % 3 - 1) * dil) + dx;
            float y0f = floorf(py), x0f = floorf(px);
            float ly = py - y0f, lx = px - x0f;
            int y0 = (int)y0f, x0 = (int)x0f;
            float v00 = dsamp2<F>(sup, ibase, y0, x0);
            float v01 = dsamp2<F>(sup, ibase, y0, x0 + 1);
            float v10 = dsamp2<F>(sup, ibase, y0 + 1, x0);
            float v11 = dsamp2<F>(sup, ibase, y0 + 1, x0 + 1);
            float val = (v00 * (1.f - lx) + v01 * lx) * (1.f - ly)
                      + (v10 * (1.f - lx) + v11 * lx) * ly;
            const float4* wr = (const float4*)&wsm[(c * 9 + t) * 28];
            #pragma unroll
            for (int u = 0; u < 7; ++u) {
                float4 w4 = wr[u];
                acc[u][0] = fmaf(val, w4.x, acc[u][0]);
                acc[u][1] = fmaf(val, w4.y, acc[u][1]);
                acc[u][2] = fmaf(val, w4.z, acc[u][2]);
                acc[u][3] = fmaf(val, w4.w, acc[u][3]);
            }
        }
    }
}

// v3: 32px x 8cg, 864 blocks, XCD swizzle. Fixes for R7's regression:
// (1) wsm staged via ~7 coalesced float4 loads/thread from prep_dw's
//     pre-transposed buffer (was 6552 scattered scalar loads per block);
// (2) red LDS deleted -> LDS 54272 -> 26208 B (6 blocks/CU capacity, so
//     the WHOLE 864-block dispatch is co-resident, no serial block tail):
//     lane<->lane^32 pair-reduce via shfl_xor (same px, adjacent cg), then
//     half-lanes atomicAdd the 4 remaining partials into pre-zeroed accws.
__global__ __launch_bounds__(256) void deform_kernel(const void* __restrict__ sup,
                                                     const u16* __restrict__ offb,
                                                     const float* __restrict__ wsp,
                                                     float* __restrict__ accws,
                                                     int dil, int m_base,
                                                     const int* __restrict__ flag) {
    int f = *flag;
    __shared__ alignas(16) float wsm[26 * 9 * 28];
    int tid = threadIdx.x;
    int bid = blockIdx.x;
    int sw = (bid & 7) * 108 + (bid >> 3);   // bijective: 864 = 8*108
    for (int i = tid; i < 1638; i += 256)
        ((float4*)wsm)[i] = ((const float4*)wsp)[i];
    __syncthreads();

    int px = tid & 31;
    int cg = tid >> 5;                 // 0..7
    int c0 = (cg * 26) >> 3;
    int c1 = ((cg + 1) * 26) >> 3;
    int ml = sw * 32 + px;
    int m = m_base + ml;
    int b = m / HW6912;
    int p = m - b * HW6912;
    int y = p / IMW;
    int x = p - y * IMW;

    f32x4 acc[7];
    #pragma unroll
    for (int u = 0; u < 7; ++u) acc[u] = (f32x4){0.f, 0.f, 0.f, 0.f};

    const u16* oc = offb + (size_t)ml * 468;
    if (f) deform_body<1>(sup, oc, wsm, acc, c0, c1, b, y, x, dil);
    else   deform_body<0>(sup, oc, wsm, acc, c0, c1, b, y, x, dil);

    // pair-reduce lane l with l^32 (same px, adjacent cg) — halves atomics
    #pragma unroll
    for (int u = 0; u < 7; ++u)
        #pragma unroll
        for (int k2 = 0; k2 < 4; ++k2) {
            float v = acc[u][k2];
            acc[u][k2] = v + __shfl_xor(v, 32);
        }

    if (!(tid & 32)) {
        float* dst = accws + (size_t)m * 32;
        #pragma unroll
        for (int u = 0; u < 7; ++u)
            #pragma unroll
            for (int k2 = 0; k2 < 4; ++k2) {
                int o = u * 4 + k2;
                if (o < 26) atomicAdd(dst + o, acc[u][k2]);
            }
    }
}

// ---------------------------------------------------------------- finalize
__global__ __launch_bounds__(256) void finalize_kernel(const float* __restrict__ accws,
                                                       void* __restrict__ out,
                                                       const int* __restrict__ flag) {
    int f = *flag;
    int q = blockIdx.x * 256 + threadIdx.x;
    int b = q / (CIN * HW6912);
    int r = q - b * (CIN * HW6912);
    int o = r / HW6912;
    int p = r - o * HW6912;
    float v = accws[(size_t)(b * HW6912 + p) * 32 + o] * 0.2f;
    if (f) ((float*)out)[q] = v;
    else   ((u16*)out)[q] = f2b(v);
}

// ---------------------------------------------------------------- host
extern "C" void kernel_launch(void* const* d_in, const int* in_sizes, int n_in,
                              void* d_out, int out_size, void* d_ws, size_t ws_size,
                              hipStream_t stream) {
    (void)in_sizes; (void)n_in; (void)out_size;
    const void* ref_x    = d_in[0];
    const void* sup_x    = d_in[1];
    const void* w1_0     = d_in[2];
    const void* w2_0     = d_in[3];
    const void* wd_0     = d_in[4];
    const void* bn1_0    = d_in[5];
    const void* bn2_0    = d_in[6];
    const void* bnd_0    = d_in[7];
    const void* w1_rest  = d_in[8];
    const void* w2_rest  = d_in[9];
    const void* bn1_rest = d_in[10];
    const void* bn2_rest = d_in[11];
    const void* offset_w = d_in[12];
    const void* deform_w = d_in[13];

    // workspace layout (bytes)
    size_t o_x0    = 0;                          // 16*98*74*32*2   =  7,426,048
    size_t o_h0    = o_x0 + 7426048;             // 16*98*74*128*2  = 29,704,192 (offb aliases)
    size_t o_h1s   = o_h0 + 29704192;            // 29,704,192
    size_t o_acc   = o_h1s + 29704192;           // 14,155,776 (pre-zeroed; deform atomicAdds)
    size_t o_wrest = o_acc + 14155776;           // 11,206,656
    size_t o_w20   = o_wrest + 11206656;         //    294,912
    size_t o_w10   = o_w20 + 294912;             //     73,728
    size_t o_wd    = o_w10 + 73728;              //      8,192
    size_t o_woff  = o_wd + 8192;                //  5,898,240
    size_t o_bias  = o_woff + 5898240;           //     20,992
    size_t o_wsall = o_bias + 20992;             //    131,072 (5*6552 floats)
    size_t o_flag  = o_wsall + 131072;           //         64
    size_t o_end   = o_flag + 64;                // 98,624,128
    if (ws_size < o_end) return;

    char* ws = (char*)d_ws;
    u16* x0    = (u16*)(ws + o_x0);
    u16* h0    = (u16*)(ws + o_h0);
    u16* offb  = (u16*)(ws + o_h0);      // alias: h0 dead once the chain finishes
    u16* h1s   = (u16*)(ws + o_h1s);
    float* accb = (float*)(ws + o_acc);
    u16* Wr    = (u16*)(ws + o_wrest);
    u16* W20   = (u16*)(ws + o_w20);
    u16* W10   = (u16*)(ws + o_w10);
    u16* Wd    = (u16*)(ws + o_wd);
    u16* Woff  = (u16*)(ws + o_woff);
    float* biasb = (float*)(ws + o_bias);
    float* wsall = (float*)(ws + o_wsall);
    int* flagp = (int*)(ws + o_flag);

    dim3 blk(256);

    probe_kernel<<<1, 64, 0, stream>>>(bn1_0, flagp);
    // zero x0 + h0 + h1s + acc (padding halos and the atomic accumulator)
    zero_ws_kernel<<<2048, blk, 0, stream>>>((uint4*)ws,
        (int)((7426048 + 2 * 29704192 + 14155776) / 16));
    fill_x0_kernel<<<432, blk, 0, stream>>>(ref_x, sup_x, x0, flagp);
    prep_rest_kernel<<<21888, blk, 0, stream>>>(w1_rest, w2_rest, bn1_rest, bn2_rest, Wr, flagp);
    prep_b0_kernel<<<736, blk, 0, stream>>>(w1_0, w2_0, wd_0, bn1_0, bn2_0, bnd_0, W20, W10, Wd, flagp);
    prep_off_kernel<<<11520, blk, 0, stream>>>(offset_w, Woff, flagp);
    prep_dw_kernel<<<128, blk, 0, stream>>>(deform_w, wsall, flagp);
    prep_bias_kernel<<<21, blk, 0, stream>>>(bn1_0, bn2_0, bnd_0, bn1_rest, bn2_rest, biasb, flagp);

    // block0: downsample (1x1 conv + BN) x0 -> h1s ; conv1 x0 -> h0
    conv_gemm<<<dim3(864, 2), blk, 0, stream>>>(x0, Wd, biasb + 2 * 128, h1s, 5, 1, 32, 0);
    conv_gemm<<<dim3(864, 2), blk, 0, stream>>>(x0, W10, biasb + 0 * 128, h0, 5, 9, 288, 1);
    // block0: conv2 + BN + idn(h1s) + relu -> h1s
    chain_conv<<<1728, blk, 0, stream>>>(h0, W20, biasb + 1 * 128, h1s, h1s, 1);

    for (int t = 0; t < 19; ++t) {
        const u16* wa = Wr + (size_t)t * 147456;
        const u16* wb = Wr + (size_t)(19 + t) * 147456;
        chain_conv<<<1728, blk, 0, stream>>>(h1s, wa, biasb + (3 + t) * 128, nullptr, h0, 1);
        chain_conv<<<1728, blk, 0, stream>>>(h0, wb, biasb + (22 + t) * 128, h1s, h1s, 1);
    }

    // 5 dilation branches, chunked over 4 batches (offb aliases h0)
    const int dils[5] = {3, 6, 12, 18, 24};
    for (int i = 0; i < 5; ++i) {
        for (int cb = 0; cb < 4; ++cb) {
            int mb = cb * 27648;
            off_conv<<<1728, blk, 0, stream>>>(h1s, Woff + (size_t)i * 589824, offb, dils[i], mb);
            deform_kernel<<<864, blk, 0, stream>>>(sup_x, offb, wsall + (size_t)i * 6552,
                                                   accb, dils[i], mb, flagp);
        }
    }
    finalize_kernel<<<11232, blk, 0, stream>>>(accb, d_out, flagp);
}

// Round 10
// 3951.965 us; speedup vs baseline: 1.6340x; 1.6340x over previous
//
#include <hip/hip_runtime.h>

typedef unsigned short u16;
typedef unsigned int u32;
typedef __bf16 bf16x8 __attribute__((ext_vector_type(8)));
typedef float f32x4 __attribute__((ext_vector_type(4)));

#define NB 16
#define CIN 26
#define IMH 96
#define IMW 72
#define HW6912 6912      // 96*72
#define NPIX 110592      // 16*6912
// small padded geom (all internal activations): 98 x 74, pad 1
#define SPH 98
#define SPW 74
#define SPAD 1

__device__ __forceinline__ float b2f(u16 h) {
    union { u32 u; float f; } x; x.u = ((u32)h) << 16; return x.f;
}
__device__ __forceinline__ u16 f2b(float f) {
    union { float f; u32 u; } x; x.f = f;
    u32 u = x.u;
    u32 r = (u + 0x7fffu + ((u >> 16) & 1u)) >> 16;
    return (u16)r;
}
__device__ __forceinline__ float ldin(const void* p, int i, int f) {
    return f ? ((const float*)p)[i] : b2f(((const u16*)p)[i]);
}

// map flat pixel m -> element offset in small padded NHWC buffer, (1<<clog2) ch
__device__ __forceinline__ int pbase(int m, int clog2) {
    int b = m / HW6912;
    int p = m - b * HW6912;
    int y = p / IMW;
    int x = p - y * IMW;
    return (((b * SPH + y + SPAD) * SPW) + (x + SPAD)) << clog2;
}

__device__ __forceinline__ void glds16(const u16* g, u16* l) {
    __builtin_amdgcn_global_load_lds(
        (const __attribute__((address_space(1))) void*)g,
        (__attribute__((address_space(3))) void*)l, 16, 0, 0);
}

// ---------------------------------------------------------------- dtype probe
__global__ void probe_kernel(const void* bn, int* flag) {
    if (threadIdx.x == 0 && blockIdx.x == 0) {
        const float* f = (const float*)bn;
        int cnt = 0;
        for (int j = 64; j < 128; ++j) {
            float v = f[j];
            if (v >= 0.4f && v <= 1.6f) cnt++;
        }
        *flag = (cnt >= 32) ? 1 : 0;
    }
}

// ---------------------------------------------------------------- zero
__global__ __launch_bounds__(256) void zero_ws_kernel(uint4* p, int n16) {
    int i = blockIdx.x * 256 + threadIdx.x;
    int stride = gridDim.x * 256;
    for (; i < n16; i += stride) p[i] = make_uint4(0u, 0u, 0u, 0u);
}

// ---------------------------------------------------------------- x0 = ref - sup -> small padded NHWC(32)
__global__ __launch_bounds__(256) void fill_x0_kernel(const void* __restrict__ ref,
                                                      const void* __restrict__ sup,
                                                      u16* __restrict__ x0,
                                                      const int* __restrict__ flag) {
    int f = *flag;
    int t = blockIdx.x * 256 + threadIdx.x;
    int b = t / HW6912;
    int p = t - b * HW6912;
    int y = p / IMW;
    int x = p - y * IMW;
    int dst = ((b * SPH + y + SPAD) * SPW + (x + SPAD)) << 5;
    #pragma unroll 1
    for (int c = 0; c < CIN; ++c) {
        int src = (b * CIN + c) * HW6912 + p;
        x0[dst + c] = f2b(ldin(ref, src, f) - ldin(sup, src, f));
    }
}

// ---------------------------------------------------------------- weight preps
// prep_rest v2: chain weights in MFMA-fragment order (harness-verified).
__global__ __launch_bounds__(256) void prep_rest_kernel(const void* __restrict__ w1r,
                                                        const void* __restrict__ w2r,
                                                        const void* __restrict__ bn1r,
                                                        const void* __restrict__ bn2r,
                                                        u16* __restrict__ dst,
                                                        const int* __restrict__ flag) {
    int f = *flag;
    int idx = blockIdx.x * 256 + threadIdx.x;        // 38*147456
    int c = idx / 147456;
    int e = idx - c * 147456;
    int ee = e & 7;
    int l = (e >> 3) & 63;
    int j = (e >> 9) & 1;
    int w2 = (e >> 10) & 1;
    int rest = e >> 11;            // 0..71
    int it = rest % 36;
    int nt = rest / 36;
    int n = nt * 64 + w2 * 32 + j * 16 + (l & 15);
    int k = it * 32 + ((l >> 4) << 3) + ee;
    int s = k >> 7, ci = k & 127;
    const void* w  = (c < 19) ? w1r : w2r;
    int wb         = ((c < 19) ? c : (c - 19)) * 147456;
    const void* bn = (c < 19) ? bn1r : bn2r;
    int bb         = ((c < 19) ? c : (c - 19)) * 512;
    float inv = ldin(bn, bb + n, f) * rsqrtf(ldin(bn, bb + 384 + n, f) + 1e-5f);
    dst[idx] = f2b(ldin(w, wb + (n * 128 + ci) * 9 + s, f) * inv);
}

__global__ __launch_bounds__(256) void prep_b0_kernel(const void* __restrict__ w1_0,
                                                      const void* __restrict__ w2_0,
                                                      const void* __restrict__ wd_0,
                                                      const void* __restrict__ bn1_0,
                                                      const void* __restrict__ bn2_0,
                                                      const void* __restrict__ bnd_0,
                                                      u16* __restrict__ W20,
                                                      u16* __restrict__ W10,
                                                      u16* __restrict__ Wd,
                                                      const int* __restrict__ flag) {
    int f = *flag;
    int idx = blockIdx.x * 256 + threadIdx.x;  // 188416
    if (idx < 147456) {
        // W20 in fragment order (for chain_conv)
        int e = idx;
        int ee = e & 7;
        int l = (e >> 3) & 63;
        int j = (e >> 9) & 1;
        int w2 = (e >> 10) & 1;
        int rest = e >> 11;
        int it = rest % 36;
        int nt = rest / 36;
        int n = nt * 64 + w2 * 32 + j * 16 + (l & 15);
        int k = it * 32 + ((l >> 4) << 3) + ee;
        int s = k >> 7, ci = k & 127;
        float inv = ldin(bn2_0, n, f) * rsqrtf(ldin(bn2_0, 384 + n, f) + 1e-5f);
        W20[idx] = f2b(ldin(w2_0, (n * 128 + ci) * 9 + s, f) * inv);
    } else if (idx < 184320) {
        int j = idx - 147456;
        int o = j / 288, k = j - o * 288;
        int s = k >> 5, ci = k & 31;
        float inv = ldin(bn1_0, o, f) * rsqrtf(ldin(bn1_0, 384 + o, f) + 1e-5f);
        W10[j] = (ci < CIN) ? f2b(ldin(w1_0, (o * CIN + ci) * 9 + s, f) * inv) : (u16)0;
    } else {
        int j = idx - 184320;
        int o = j >> 5, ci = j & 31;
        float inv = ldin(bnd_0, o, f) * rsqrtf(ldin(bnd_0, 384 + o, f) + 1e-5f);
        Wd[j] = (ci < CIN) ? f2b(ldin(wd_0, o * CIN + ci, f) * inv) : (u16)0;
    }
}

// prep_off v2: store W in MFMA-fragment order (B direct-to-VGPR in off_conv).
__global__ __launch_bounds__(256) void prep_off_kernel(const void* __restrict__ offw,
                                                       u16* __restrict__ dst,
                                                       const int* __restrict__ flag) {
    int f = *flag;
    int idx = blockIdx.x * 256 + threadIdx.x;    // 5*8*36*2*2*512 = 2,949,120
    int e = idx & 7;
    int l = (idx >> 3) & 63;
    int j = (idx >> 9) & 1;
    int w2 = (idx >> 10) & 1;
    int rest = idx >> 11;
    int it = rest % 36;
    int dnt = rest / 36;
    int nt = dnt & 7;
    int d = dnt >> 3;
    int n = nt * 64 + w2 * 32 + j * 16 + (l & 15);
    int k = it * 32 + (l >> 4) * 8 + e;
    int s = k >> 7, ci = k & 127;
    dst[idx] = (n < 468) ? f2b(ldin(offw, ((d * 468 + n) * 128 + ci) * 9 + s, f)) : (u16)0;
}

// prep_dw: deform weights -> [5][26ch c][9 tap][28 o-padded] float for
// coalesced float4 wsm staging (R8-proven: FETCH 26->14.7 MB).
__global__ __launch_bounds__(256) void prep_dw_kernel(const void* __restrict__ dwall,
                                                      float* __restrict__ dst,
                                                      const int* __restrict__ flag) {
    int f = *flag;
    int idx = blockIdx.x * 256 + threadIdx.x;    // 5*6552 = 32760
    if (idx >= 32760) return;
    int d = idx / 6552;
    int r = idx - d * 6552;
    int o = r % 28;
    int ct = r / 28;
    int c = ct / 9, t = ct - c * 9;
    dst[idx] = (o < CIN) ? ldin(dwall, d * 6084 + (o * CIN + c) * 9 + t, f) : 0.f;
}

__global__ __launch_bounds__(256) void prep_bias_kernel(const void* __restrict__ bn1_0,
                                                        const void* __restrict__ bn2_0,
                                                        const void* __restrict__ bnd_0,
                                                        const void* __restrict__ bn1r,
                                                        const void* __restrict__ bn2r,
                                                        float* __restrict__ dst,
                                                        const int* __restrict__ flag) {
    int f = *flag;
    int idx = blockIdx.x * 256 + threadIdx.x;
    if (idx >= 41 * 128) return;
    int set = idx >> 7;
    int o = idx & 127;
    const void* bn; int bb = 0;
    if (set == 0) bn = bn1_0;
    else if (set == 1) bn = bn2_0;
    else if (set == 2) bn = bnd_0;
    else if (set < 22) { bn = bn1r; bb = (set - 3) * 512; }
    else { bn = bn2r; bb = (set - 22) * 512; }
    float s = ldin(bn, bb + o, f), b = ldin(bn, bb + 128 + o, f);
    float mu = ldin(bn, bb + 256 + o, f), v = ldin(bn, bb + 384 + o, f);
    float inv = s * rsqrtf(v + 1e-5f);
    dst[idx] = b - mu * inv;
}

// ---------------------------------------------------------------- generic implicit-GEMM conv (R7 structure)
// Used only for the two cheap x0 convs (K=32 / K=288).
__global__ __launch_bounds__(256) void conv_gemm(const u16* __restrict__ A,
                                                 const u16* __restrict__ W,
                                                 const float* __restrict__ bias,
                                                 u16* __restrict__ out,
                                                 int clog2, int nslab, int K,
                                                 int relu) {
    __shared__ u16 As[2][128 * 32];
    __shared__ u16 Bs[2][64 * 32];
    int tid = threadIdx.x;
    int m0 = blockIdx.x * 128;
    int n0 = blockIdx.y * 64;
    int Cin = 1 << clog2;

    int r0 = tid >> 2;
    int q8 = (tid & 3) * 8;
    int arow0 = pbase(m0 + r0, clog2) + q8;
    int arow1 = pbase(m0 + r0 + 64, clog2) + q8;
    int brow0 = (n0 + r0) * K + q8;
    int l8 = tid * 8;

    f32x4 acc[4][2];
    #pragma unroll
    for (int i = 0; i < 4; ++i)
        #pragma unroll
        for (int j = 0; j < 2; ++j)
            acc[i][j] = (f32x4){0.f, 0.f, 0.f, 0.f};

    int wid = tid >> 6;
    int wm = (wid >> 1) * 64;
    int wn = (wid & 1) * 32;
    int lane = tid & 63;
    int lr = lane & 15;
    int lq = lane >> 4;

    int nk = K >> 5;
    auto stage = [&](int buf, int kt) {
        int sl = kt >> clog2;
        int win = kt & (Cin - 1);
        int soff = 0;
        if (nslab == 9) {
            int d3 = sl / 3;
            soff = (((d3 - 1) * SPW + (sl - d3 * 3 - 1))) << clog2;
        }
        glds16(A + arow0 + soff + win, &As[buf][l8]);
        glds16(A + arow1 + soff + win, &As[buf][2048 + l8]);
        glds16(W + brow0 + kt, &Bs[buf][l8]);
    };

    stage(0, 0);
    #pragma unroll 1
    for (int it = 0; it < nk; ++it) {
        __syncthreads();
        if (it + 1 < nk) stage((it + 1) & 1, (it + 1) << 5);
        const u16* as = As[it & 1];
        const u16* bs = Bs[it & 1];
        bf16x8 af[4], bfr[2];
        #pragma unroll
        for (int i = 0; i < 4; ++i)
            af[i] = *(const bf16x8*)&as[(wm + i * 16 + lr) * 32 + lq * 8];
        #pragma unroll
        for (int j = 0; j < 2; ++j)
            bfr[j] = *(const bf16x8*)&bs[(wn + j * 16 + lr) * 32 + lq * 8];
        #pragma unroll
        for (int i = 0; i < 4; ++i)
            #pragma unroll
            for (int j = 0; j < 2; ++j)
                acc[i][j] = __builtin_amdgcn_mfma_f32_16x16x32_bf16(af[i], bfr[j], acc[i][j], 0, 0, 0);
    }

    #pragma unroll
    for (int i = 0; i < 4; ++i) {
        #pragma unroll
        for (int r = 0; r < 4; ++r) {
            int ml = m0 + wm + i * 16 + lq * 4 + r;
            int ob = pbase(ml, 7);
            #pragma unroll
            for (int j = 0; j < 2; ++j) {
                int n = n0 + wn + j * 16 + lr;
                float v = acc[i][j][r] + bias[n];
                if (relu) v = fmaxf(v, 0.f);
                out[ob + n] = f2b(v);
            }
        }
    }
}

// ---------------------------------------------------------------- chain conv (dil=1, 128ch in, 128ch out, K=1152)
// v6: XCD-locality swizzle (each XCD owns 108 contiguous mt = 2 images).
__global__ __launch_bounds__(256, 8) void chain_conv(const u16* __restrict__ A,
                                                     const u16* __restrict__ W,   // frag-ordered [2][36][2][2][512]
                                                     const float* __restrict__ bias,
                                                     const u16* __restrict__ idn,
                                                     u16* __restrict__ out,
                                                     int relu) {
    __shared__ u16 As[2][128 * 32];
    int tid = threadIdx.x;
    int wg = blockIdx.x;
    int sw = (wg & 7) * 216 + (wg >> 3);   // bijective: 1728 = 8*216
    int mt = sw >> 1, nt = sw & 1;
    int m0 = mt * 128, n0 = nt * 64;

    int r0 = tid >> 2;
    int q8 = (tid & 3) * 8;
    int pbq[2];
    #pragma unroll
    for (int q = 0; q < 2; ++q) {
        int p = m0 + r0 + q * 64;
        int b = p / HW6912;
        int rem = p - b * HW6912;
        int y = rem / IMW;
        int x = rem - y * IMW;
        pbq[q] = ((b * SPH + y + 1) * SPW + (x + 1)) * 128;
    }
    int l8 = tid * 8;

    f32x4 acc[4][2];
    #pragma unroll
    for (int i = 0; i < 4; ++i) {
        acc[i][0] = (f32x4){0.f, 0.f, 0.f, 0.f};
        acc[i][1] = (f32x4){0.f, 0.f, 0.f, 0.f};
    }

    int wid = tid >> 6;
    int wm = (wid >> 1) * 64;
    int w2 = wid & 1;
    int wn = w2 * 32;
    int lane = tid & 63;
    int lr = lane & 15;
    int lq = lane >> 4;

    // fragment-ordered W base for this wave: + it*2048 + j*512 per fragment
    const u16* wv = W + nt * 73728 + w2 * 1024 + lane * 8;

    auto stage = [&](int buf, int kt) {
        int sl = kt >> 7;           // tap 0..8
        int win = kt & 127;
        int d3 = sl / 3;
        int soff = ((d3 - 1) * SPW + (sl - d3 * 3 - 1)) * 128;
        glds16(A + pbq[0] + soff + win + q8, &As[buf][l8]);
        glds16(A + pbq[1] + soff + win + q8, &As[buf][2048 + l8]);
    };

    stage(0, 0);
    #pragma unroll 1
    for (int it = 0; it < 36; ++it) {
        __syncthreads();
        if (it + 1 < 36) stage((it + 1) & 1, (it + 1) << 5);
        const u16* as = As[it & 1];
        bf16x8 af[4], bfr[2];
        #pragma unroll
        for (int i = 0; i < 4; ++i)
            af[i] = *(const bf16x8*)&as[(wm + i * 16 + lr) * 32 + lq * 8];
        bfr[0] = *(const bf16x8*)(wv + it * 2048);
        bfr[1] = *(const bf16x8*)(wv + it * 2048 + 512);
        #pragma unroll
        for (int i = 0; i < 4; ++i)
            #pragma unroll
            for (int j = 0; j < 2; ++j)
                acc[i][j] = __builtin_amdgcn_mfma_f32_16x16x32_bf16(af[i], bfr[j], acc[i][j], 0, 0, 0);
    }

    #pragma unroll
    for (int i = 0; i < 4; ++i) {
        #pragma unroll
        for (int r = 0; r < 4; ++r) {
            int ml = m0 + wm + i * 16 + lq * 4 + r;
            int ob = pbase(ml, 7);
            #pragma unroll
            for (int j = 0; j < 2; ++j) {
                int n = n0 + wn + j * 16 + lr;
                float v = acc[i][j][r] + bias[n];
                if (idn) v += b2f(idn[ob + n]);
                if (relu) v = fmaxf(v, 0.f);
                out[ob + n] = f2b(v);
            }
        }
    }
}

// ---------------------------------------------------------------- offset conv (dilated, reads h1s with explicit zero-pad)
// v3: XCD-locality swizzle (27 mt per XCD, 8 nt-tiles adjacent).
__global__ __launch_bounds__(256, 8) void off_conv(const u16* __restrict__ A,   // h1s
                                                   const u16* __restrict__ W,   // frag-ordered [nt][it][w2][j][64*8]
                                                   u16* __restrict__ out,       // [m_local][468]
                                                   int dil, int m_base) {
    __shared__ u16 As[2][128 * 32];
    int tid = threadIdx.x;
    int wg = blockIdx.x;
    int sw = (wg & 7) * 216 + (wg >> 3);   // bijective: 1728 = 8*216
    int mt = sw >> 3, nt = sw & 7;
    int m0 = mt * 128, n0 = nt * 64;

    int r0 = tid >> 2;
    int q8 = (tid & 3) * 8;
    int pb2[2], py[2], px[2];
    #pragma unroll
    for (int q = 0; q < 2; ++q) {
        int p = m_base + m0 + r0 + q * 64;
        int b = p / HW6912;
        int rem = p - b * HW6912;
        pb2[q] = b;
        py[q] = rem / IMW;
        px[q] = rem - py[q] * IMW;
    }
    int l8 = tid * 8;

    f32x4 acc[4][2];
    #pragma unroll
    for (int i = 0; i < 4; ++i) {
        acc[i][0] = (f32x4){0.f, 0.f, 0.f, 0.f};
        acc[i][1] = (f32x4){0.f, 0.f, 0.f, 0.f};
    }

    int wid = tid >> 6;
    int wm = (wid >> 1) * 64;
    int wn = (wid & 1) * 32;
    int lane = tid & 63;
    int lr = lane & 15;
    int lq = lane >> 4;

    // fragment-ordered W base for this wave: + it*2048 + j*512 per fragment
    const u16* wv = W + nt * 73728 + (wid & 1) * 1024 + lane * 8;

    auto stage = [&](int buf, int kt) {
        int sl = kt >> 7;
        int win = kt & 127;
        int d3 = sl / 3;
        int dy = (d3 - 1) * dil, dx = (sl - d3 * 3 - 1) * dil;
        #pragma unroll
        for (int q = 0; q < 2; ++q) {
            int y2 = py[q] + dy, x2 = px[q] + dx;
            uint4 v = make_uint4(0u, 0u, 0u, 0u);
            if (y2 >= 0 && y2 < IMH && x2 >= 0 && x2 < IMW)
                v = *(const uint4*)(A + ((pb2[q] * SPH + y2 + 1) * SPW + x2 + 1) * 128 + win + q8);
            *(uint4*)&As[buf][q * 2048 + l8] = v;
        }
    };

    stage(0, 0);
    #pragma unroll 1
    for (int it = 0; it < 36; ++it) {
        __syncthreads();
        if (it + 1 < 36) stage((it + 1) & 1, (it + 1) << 5);
        const u16* as = As[it & 1];
        bf16x8 af[4], bfr[2];
        #pragma unroll
        for (int i = 0; i < 4; ++i)
            af[i] = *(const bf16x8*)&as[(wm + i * 16 + lr) * 32 + lq * 8];
        bfr[0] = *(const bf16x8*)(wv + it * 2048);
        bfr[1] = *(const bf16x8*)(wv + it * 2048 + 512);
        #pragma unroll
        for (int i = 0; i < 4; ++i)
            #pragma unroll
            for (int j = 0; j < 2; ++j)
                acc[i][j] = __builtin_amdgcn_mfma_f32_16x16x32_bf16(af[i], bfr[j], acc[i][j], 0, 0, 0);
    }

    #pragma unroll
    for (int i = 0; i < 4; ++i) {
        #pragma unroll
        for (int r = 0; r < 4; ++r) {
            int ml = m0 + wm + i * 16 + lq * 4 + r;
            int ob = ml * 468;
            #pragma unroll
            for (int j = 0; j < 2; ++j) {
                int n = n0 + wn + j * 16 + lr;
                if (n < 468) out[ob + n] = f2b(acc[i][j][r]);
            }
        }
    }
}

// ---------------------------------------------------------------- deformable conv
template <int F>
__device__ __forceinline__ float dsamp2(const void* sup, int base, int yi, int xi) {
    bool ok = (yi >= 0) & (yi < IMH) & (xi >= 0) & (xi < IMW);
    int yc = yi < 0 ? 0 : (yi > IMH - 1 ? IMH - 1 : yi);
    int xc = xi < 0 ? 0 : (xi > IMW - 1 ? IMW - 1 : xi);
    float v = F ? ((const float*)sup)[base + yc * IMW + xc]
                : b2f(((const u16*)sup)[base + yc * IMW + xc]);
    return ok ? v : 0.f;
}

template <int F>
__device__ __forceinline__ void deform_body(const void* __restrict__ sup,
                                            const u16* __restrict__ oc,
                                            const float* __restrict__ wsm,
                                            f32x4 acc[7],
                                            int c0, int c1, int b, int y, int x, int dil) {
    #pragma unroll 1
    for (int c = c0; c < c1; ++c) {
        int ibase = (b * CIN + c) * HW6912;
        #pragma unroll
        for (int t = 0; t < 9; ++t) {
            u32 pr = *(const u32*)(oc + c * 18 + t * 2);
            float dy = b2f((u16)(pr & 0xffffu));
            float dx = b2f((u16)(pr >> 16));
            float py = (float)(y + (t / 3 - 1) * dil) + dy;
            float px = (float)(x + (t % 3 - 1) * dil) + dx;
            float y0f = floorf(py), x0f = floorf(px);
            float ly = py - y0f, lx = px - x0f;
            int y0 = (int)y0f, x0 = (int)x0f;
            float v00 = dsamp2<F>(sup, ibase, y0, x0);
            float v01 = dsamp2<F>(sup, ibase, y0, x0 + 1);
            float v10 = dsamp2<F>(sup, ibase, y0 + 1, x0);
            float v11 = dsamp2<F>(sup, ibase, y0 + 1, x0 + 1);
            float val = (v00 * (1.f - lx) + v01 * lx) * (1.f - ly)
                      + (v10 * (1.f - lx) + v11 * lx) * ly;
            const float4* wr = (const float4*)&wsm[(c * 9 + t) * 28];
            #pragma unroll
            for (int u = 0; u < 7; ++u) {
                float4 w4 = wr[u];
                acc[u][0] = fmaf(val, w4.x, acc[u][0]);
                acc[u][1] = fmaf(val, w4.y, acc[u][1]);
                acc[u][2] = fmaf(val, w4.z, acc[u][2]);
                acc[u][3] = fmaf(val, w4.w, acc[u][3]);
            }
        }
    }
}

// v4: 32px x 8cg, 864 blocks, XCD swizzle, NO atomics (R8's 87.7MB atomic
// write traffic was the regression). px=tid&31, cg=tid>>5: each wave holds
// cg-pair (2w,2w+1) of the same 32 px -> shfl_xor(32) pair-reduce in-register;
// only 4 partials/px go to LDS red[4][32][27] (stride 27 coprime 32 ->
// conflict-free; 13.8KB). LDS total 40032 B -> 4 blocks/CU, grid 864 = 3.4
// blocks/CU -> whole dispatch co-resident. Final: plain store w/ first flag.
// wsm staged coalesced from prep_dw (R8-proven).
__global__ __launch_bounds__(256) void deform_kernel(const void* __restrict__ sup,
                                                     const u16* __restrict__ offb,
                                                     const float* __restrict__ wsp,
                                                     float* __restrict__ accws,
                                                     int dil, int first, int m_base,
                                                     const int* __restrict__ flag) {
    int f = *flag;
    __shared__ alignas(16) float wsm[26 * 9 * 28];
    __shared__ float red[4 * 32 * 27];
    int tid = threadIdx.x;
    int bid = blockIdx.x;
    int sw = (bid & 7) * 108 + (bid >> 3);   // bijective: 864 = 8*108
    for (int i = tid; i < 1638; i += 256)
        ((float4*)wsm)[i] = ((const float4*)wsp)[i];
    __syncthreads();

    int px = tid & 31;
    int cg = tid >> 5;                 // 0..7
    int c0 = (cg * 26) >> 3;
    int c1 = ((cg + 1) * 26) >> 3;
    int ml = sw * 32 + px;
    int m = m_base + ml;
    int b = m / HW6912;
    int p = m - b * HW6912;
    int y = p / IMW;
    int x = p - y * IMW;

    f32x4 acc[7];
    #pragma unroll
    for (int u = 0; u < 7; ++u) acc[u] = (f32x4){0.f, 0.f, 0.f, 0.f};

    const u16* oc = offb + (size_t)ml * 468;
    if (f) deform_body<1>(sup, oc, wsm, acc, c0, c1, b, y, x, dil);
    else   deform_body<0>(sup, oc, wsm, acc, c0, c1, b, y, x, dil);

    // in-wave pair-reduce: lane l <-> l^32 (same px, cg pair 2w/2w+1)
    #pragma unroll
    for (int u = 0; u < 7; ++u)
        #pragma unroll
        for (int k2 = 0; k2 < 4; ++k2) {
            float v = acc[u][k2];
            acc[u][k2] = v + __shfl_xor(v, 32);
        }

    int w = tid >> 6;                  // wave 0..3
    if (!(tid & 32)) {                 // lanes 0-31 of each wave hold the pair sum
        float* mr = red + (w * 32 + px) * 27;
        #pragma unroll
        for (int u = 0; u < 7; ++u)
            #pragma unroll
            for (int k2 = 0; k2 < 4; ++k2) {
                int o = u * 4 + k2;
                if (o < 26) mr[o] = acc[u][k2];
            }
    }
    __syncthreads();

    int base_m = m_base + sw * 32;
    for (int v = tid; v < 32 * 26; v += 256) {
        int ppx = v / 26;
        int o = v - ppx * 26;
        float s = red[(0 * 32 + ppx) * 27 + o] + red[(1 * 32 + ppx) * 27 + o]
                + red[(2 * 32 + ppx) * 27 + o] + red[(3 * 32 + ppx) * 27 + o];
        size_t ai = (size_t)(base_m + ppx) * 32 + o;
        if (first) accws[ai] = s;
        else       accws[ai] += s;
    }
}

// ---------------------------------------------------------------- finalize
__global__ __launch_bounds__(256) void finalize_kernel(const float* __restrict__ accws,
                                                       void* __restrict__ out,
                                                       const int* __restrict__ flag) {
    int f = *flag;
    int q = blockIdx.x * 256 + threadIdx.x;
    int b = q / (CIN * HW6912);
    int r = q - b * (CIN * HW6912);
    int o = r / HW6912;
    int p = r - o * HW6912;
    float v = accws[(size_t)(b * HW6912 + p) * 32 + o] * 0.2f;
    if (f) ((float*)out)[q] = v;
    else   ((u16*)out)[q] = f2b(v);
}

// ---------------------------------------------------------------- host
extern "C" void kernel_launch(void* const* d_in, const int* in_sizes, int n_in,
                              void* d_out, int out_size, void* d_ws, size_t ws_size,
                              hipStream_t stream) {
    (void)in_sizes; (void)n_in; (void)out_size;
    const void* ref_x    = d_in[0];
    const void* sup_x    = d_in[1];
    const void* w1_0     = d_in[2];
    const void* w2_0     = d_in[3];
    const void* wd_0     = d_in[4];
    const void* bn1_0    = d_in[5];
    const void* bn2_0    = d_in[6];
    const void* bnd_0    = d_in[7];
    const void* w1_rest  = d_in[8];
    const void* w2_rest  = d_in[9];
    const void* bn1_rest = d_in[10];
    const void* bn2_rest = d_in[11];
    const void* offset_w = d_in[12];
    const void* deform_w = d_in[13];

    // workspace layout (bytes)
    size_t o_x0    = 0;                          // 16*98*74*32*2   =  7,426,048
    size_t o_h0    = o_x0 + 7426048;             // 16*98*74*128*2  = 29,704,192 (offb aliases)
    size_t o_h1s   = o_h0 + 29704192;            // 29,704,192
    size_t o_acc   = o_h1s + 29704192;           // 14,155,776
    size_t o_wrest = o_acc + 14155776;           // 11,206,656
    size_t o_w20   = o_wrest + 11206656;         //    294,912
    size_t o_w10   = o_w20 + 294912;             //     73,728
    size_t o_wd    = o_w10 + 73728;              //      8,192
    size_t o_woff  = o_wd + 8192;                //  5,898,240
    size_t o_bias  = o_woff + 5898240;           //     20,992
    size_t o_wsall = o_bias + 20992;             //    131,072 (5*6552 floats)
    size_t o_flag  = o_wsall + 131072;           //         64
    size_t o_end   = o_flag + 64;                // 98,624,128
    if (ws_size < o_end) return;

    char* ws = (char*)d_ws;
    u16* x0    = (u16*)(ws + o_x0);
    u16* h0    = (u16*)(ws + o_h0);
    u16* offb  = (u16*)(ws + o_h0);      // alias: h0 dead once the chain finishes
    u16* h1s   = (u16*)(ws + o_h1s);
    float* accb = (float*)(ws + o_acc);
    u16* Wr    = (u16*)(ws + o_wrest);
    u16* W20   = (u16*)(ws + o_w20);
    u16* W10   = (u16*)(ws + o_w10);
    u16* Wd    = (u16*)(ws + o_wd);
    u16* Woff  = (u16*)(ws + o_woff);
    float* biasb = (float*)(ws + o_bias);
    float* wsall = (float*)(ws + o_wsall);
    int* flagp = (int*)(ws + o_flag);

    dim3 blk(256);

    probe_kernel<<<1, 64, 0, stream>>>(bn1_0, flagp);
    // zero x0 + h0 + h1s (padding halos must be zero)
    zero_ws_kernel<<<2048, blk, 0, stream>>>((uint4*)ws, (int)((7426048 + 2 * 29704192) / 16));
    fill_x0_kernel<<<432, blk, 0, stream>>>(ref_x, sup_x, x0, flagp);
    prep_rest_kernel<<<21888, blk, 0, stream>>>(w1_rest, w2_rest, bn1_rest, bn2_rest, Wr, flagp);
    prep_b0_kernel<<<736, blk, 0, stream>>>(w1_0, w2_0, wd_0, bn1_0, bn2_0, bnd_0, W20, W10, Wd, flagp);
    prep_off_kernel<<<11520, blk, 0, stream>>>(offset_w, Woff, flagp);
    prep_dw_kernel<<<128, blk, 0, stream>>>(deform_w, wsall, flagp);
    prep_bias_kernel<<<21, blk, 0, stream>>>(bn1_0, bn2_0, bnd_0, bn1_rest, bn2_rest, biasb, flagp);

    // block0: downsample (1x1 conv + BN) x0 -> h1s ; conv1 x0 -> h0
    conv_gemm<<<dim3(864, 2), blk, 0, stream>>>(x0, Wd, biasb + 2 * 128, h1s, 5, 1, 32, 0);
    conv_gemm<<<dim3(864, 2), blk, 0, stream>>>(x0, W10, biasb + 0 * 128, h0, 5, 9, 288, 1);
    // block0: conv2 + BN + idn(h1s) + relu -> h1s
    chain_conv<<<1728, blk, 0, stream>>>(h0, W20, biasb + 1 * 128, h1s, h1s, 1);

    for (int t = 0; t < 19; ++t) {
        const u16* wa = Wr + (size_t)t * 147456;
        const u16* wb = Wr + (size_t)(19 + t) * 147456;
        chain_conv<<<1728, blk, 0, stream>>>(h1s, wa, biasb + (3 + t) * 128, nullptr, h0, 1);
        chain_conv<<<1728, blk, 0, stream>>>(h0, wb, biasb + (22 + t) * 128, h1s, h1s, 1);
    }

    // 5 dilation branches, chunked over 4 batches (offb aliases h0)
    const int dils[5] = {3, 6, 12, 18, 24};
    for (int i = 0; i < 5; ++i) {
        for (int cb = 0; cb < 4; ++cb) {
            int mb = cb * 27648;
            off_conv<<<1728, blk, 0, stream>>>(h1s, Woff + (size_t)i * 589824, offb, dils[i], mb);
            deform_kernel<<<864, blk, 0, stream>>>(sup_x, offb, wsall + (size_t)i * 6552,
                                                   accb, dils[i], (i == 0) ? 1 : 0, mb, flagp);
        }
    }
    finalize_kernel<<<11232, blk, 0, stream>>>(accb, d_out, flagp);
}

// Round 11
// 3723.078 us; speedup vs baseline: 1.7344x; 1.0615x over previous
//
#include <hip/hip_runtime.h>

typedef unsigned short u16;
typedef unsigned int u32;
typedef __bf16 bf16x8 __attribute__((ext_vector_type(8)));
typedef float f32x4 __attribute__((ext_vector_type(4)));

#define NB 16
#define CIN 26
#define IMH 96
#define IMW 72
#define HW6912 6912      // 96*72
#define NPIX 110592      // 16*6912
// small padded geom (all internal activations): 98 x 74, pad 1
#define SPH 98
#define SPW 74
#define SPAD 1

__device__ __forceinline__ float b2f(u16 h) {
    union { u32 u; float f; } x; x.u = ((u32)h) << 16; return x.f;
}
__device__ __forceinline__ u16 f2b(float f) {
    union { float f; u32 u; } x; x.f = f;
    u32 u = x.u;
    u32 r = (u + 0x7fffu + ((u >> 16) & 1u)) >> 16;
    return (u16)r;
}
__device__ __forceinline__ float ldin(const void* p, int i, int f) {
    return f ? ((const float*)p)[i] : b2f(((const u16*)p)[i]);
}

// map flat pixel m -> element offset in small padded NHWC buffer, (1<<clog2) ch
__device__ __forceinline__ int pbase(int m, int clog2) {
    int b = m / HW6912;
    int p = m - b * HW6912;
    int y = p / IMW;
    int x = p - y * IMW;
    return (((b * SPH + y + SPAD) * SPW) + (x + SPAD)) << clog2;
}

__device__ __forceinline__ void glds16(const u16* g, u16* l) {
    __builtin_amdgcn_global_load_lds(
        (const __attribute__((address_space(1))) void*)g,
        (__attribute__((address_space(3))) void*)l, 16, 0, 0);
}

// ---------------------------------------------------------------- dtype probe
__global__ void probe_kernel(const void* bn, int* flag) {
    if (threadIdx.x == 0 && blockIdx.x == 0) {
        const float* f = (const float*)bn;
        int cnt = 0;
        for (int j = 64; j < 128; ++j) {
            float v = f[j];
            if (v >= 0.4f && v <= 1.6f) cnt++;
        }
        *flag = (cnt >= 32) ? 1 : 0;
    }
}

// ---------------------------------------------------------------- zero
__global__ __launch_bounds__(256) void zero_ws_kernel(uint4* p, int n16) {
    int i = blockIdx.x * 256 + threadIdx.x;
    int stride = gridDim.x * 256;
    for (; i < n16; i += stride) p[i] = make_uint4(0u, 0u, 0u, 0u);
}

// ---------------------------------------------------------------- x0 = ref - sup -> small padded NHWC(32)
__global__ __launch_bounds__(256) void fill_x0_kernel(const void* __restrict__ ref,
                                                      const void* __restrict__ sup,
                                                      u16* __restrict__ x0,
                                                      const int* __restrict__ flag) {
    int f = *flag;
    int t = blockIdx.x * 256 + threadIdx.x;
    int b = t / HW6912;
    int p = t - b * HW6912;
    int y = p / IMW;
    int x = p - y * IMW;
    int dst = ((b * SPH + y + SPAD) * SPW + (x + SPAD)) << 5;
    #pragma unroll 1
    for (int c = 0; c < CIN; ++c) {
        int src = (b * CIN + c) * HW6912 + p;
        x0[dst + c] = f2b(ldin(ref, src, f) - ldin(sup, src, f));
    }
}

// ---------------------------------------------------------------- weight preps
// prep_rest v2: chain weights in MFMA-fragment order (harness-verified).
__global__ __launch_bounds__(256) void prep_rest_kernel(const void* __restrict__ w1r,
                                                        const void* __restrict__ w2r,
                                                        const void* __restrict__ bn1r,
                                                        const void* __restrict__ bn2r,
                                                        u16* __restrict__ dst,
                                                        const int* __restrict__ flag) {
    int f = *flag;
    int idx = blockIdx.x * 256 + threadIdx.x;        // 38*147456
    int c = idx / 147456;
    int e = idx - c * 147456;
    int ee = e & 7;
    int l = (e >> 3) & 63;
    int j = (e >> 9) & 1;
    int w2 = (e >> 10) & 1;
    int rest = e >> 11;            // 0..71
    int it = rest % 36;
    int nt = rest / 36;
    int n = nt * 64 + w2 * 32 + j * 16 + (l & 15);
    int k = it * 32 + ((l >> 4) << 3) + ee;
    int s = k >> 7, ci = k & 127;
    const void* w  = (c < 19) ? w1r : w2r;
    int wb         = ((c < 19) ? c : (c - 19)) * 147456;
    const void* bn = (c < 19) ? bn1r : bn2r;
    int bb         = ((c < 19) ? c : (c - 19)) * 512;
    float inv = ldin(bn, bb + n, f) * rsqrtf(ldin(bn, bb + 384 + n, f) + 1e-5f);
    dst[idx] = f2b(ldin(w, wb + (n * 128 + ci) * 9 + s, f) * inv);
}

__global__ __launch_bounds__(256) void prep_b0_kernel(const void* __restrict__ w1_0,
                                                      const void* __restrict__ w2_0,
                                                      const void* __restrict__ wd_0,
                                                      const void* __restrict__ bn1_0,
                                                      const void* __restrict__ bn2_0,
                                                      const void* __restrict__ bnd_0,
                                                      u16* __restrict__ W20,
                                                      u16* __restrict__ W10,
                                                      u16* __restrict__ Wd,
                                                      const int* __restrict__ flag) {
    int f = *flag;
    int idx = blockIdx.x * 256 + threadIdx.x;  // 188416
    if (idx < 147456) {
        // W20 in fragment order (for chain_conv)
        int e = idx;
        int ee = e & 7;
        int l = (e >> 3) & 63;
        int j = (e >> 9) & 1;
        int w2 = (e >> 10) & 1;
        int rest = e >> 11;
        int it = rest % 36;
        int nt = rest / 36;
        int n = nt * 64 + w2 * 32 + j * 16 + (l & 15);
        int k = it * 32 + ((l >> 4) << 3) + ee;
        int s = k >> 7, ci = k & 127;
        float inv = ldin(bn2_0, n, f) * rsqrtf(ldin(bn2_0, 384 + n, f) + 1e-5f);
        W20[idx] = f2b(ldin(w2_0, (n * 128 + ci) * 9 + s, f) * inv);
    } else if (idx < 184320) {
        int j = idx - 147456;
        int o = j / 288, k = j - o * 288;
        int s = k >> 5, ci = k & 31;
        float inv = ldin(bn1_0, o, f) * rsqrtf(ldin(bn1_0, 384 + o, f) + 1e-5f);
        W10[j] = (ci < CIN) ? f2b(ldin(w1_0, (o * CIN + ci) * 9 + s, f) * inv) : (u16)0;
    } else {
        int j = idx - 184320;
        int o = j >> 5, ci = j & 31;
        float inv = ldin(bnd_0, o, f) * rsqrtf(ldin(bnd_0, 384 + o, f) + 1e-5f);
        Wd[j] = (ci < CIN) ? f2b(ldin(wd_0, o * CIN + ci, f) * inv) : (u16)0;
    }
}

// prep_off v2: store W in MFMA-fragment order (B direct-to-VGPR in off_conv).
__global__ __launch_bounds__(256) void prep_off_kernel(const void* __restrict__ offw,
                                                       u16* __restrict__ dst,
                                                       const int* __restrict__ flag) {
    int f = *flag;
    int idx = blockIdx.x * 256 + threadIdx.x;    // 5*8*36*2*2*512 = 2,949,120
    int e = idx & 7;
    int l = (idx >> 3) & 63;
    int j = (idx >> 9) & 1;
    int w2 = (idx >> 10) & 1;
    int rest = idx >> 11;
    int it = rest % 36;
    int dnt = rest / 36;
    int nt = dnt & 7;
    int d = dnt >> 3;
    int n = nt * 64 + w2 * 32 + j * 16 + (l & 15);
    int k = it * 32 + (l >> 4) * 8 + e;
    int s = k >> 7, ci = k & 127;
    dst[idx] = (n < 468) ? f2b(ldin(offw, ((d * 468 + n) * 128 + ci) * 9 + s, f)) : (u16)0;
}

// prep_dw: deform weights -> [5][26ch c][9 tap][28 o-padded] float for
// coalesced float4 wsm staging (R8-proven: FETCH 26->14.7 MB).
__global__ __launch_bounds__(256) void prep_dw_kernel(const void* __restrict__ dwall,
                                                      float* __restrict__ dst,
                                                      const int* __restrict__ flag) {
    int f = *flag;
    int idx = blockIdx.x * 256 + threadIdx.x;    // 5*6552 = 32760
    if (idx >= 32760) return;
    int d = idx / 6552;
    int r = idx - d * 6552;
    int o = r % 28;
    int ct = r / 28;
    int c = ct / 9, t = ct - c * 9;
    dst[idx] = (o < CIN) ? ldin(dwall, d * 6084 + (o * CIN + c) * 9 + t, f) : 0.f;
}

__global__ __launch_bounds__(256) void prep_bias_kernel(const void* __restrict__ bn1_0,
                                                        const void* __restrict__ bn2_0,
                                                        const void* __restrict__ bnd_0,
                                                        const void* __restrict__ bn1r,
                                                        const void* __restrict__ bn2r,
                                                        float* __restrict__ dst,
                                                        const int* __restrict__ flag) {
    int f = *flag;
    int idx = blockIdx.x * 256 + threadIdx.x;
    if (idx >= 41 * 128) return;
    int set = idx >> 7;
    int o = idx & 127;
    const void* bn; int bb = 0;
    if (set == 0) bn = bn1_0;
    else if (set == 1) bn = bn2_0;
    else if (set == 2) bn = bnd_0;
    else if (set < 22) { bn = bn1r; bb = (set - 3) * 512; }
    else { bn = bn2r; bb = (set - 22) * 512; }
    float s = ldin(bn, bb + o, f), b = ldin(bn, bb + 128 + o, f);
    float mu = ldin(bn, bb + 256 + o, f), v = ldin(bn, bb + 384 + o, f);
    float inv = s * rsqrtf(v + 1e-5f);
    dst[idx] = b - mu * inv;
}

// ---------------------------------------------------------------- generic implicit-GEMM conv (R7 structure)
// Used only for the two cheap x0 convs (K=32 / K=288).
__global__ __launch_bounds__(256) void conv_gemm(const u16* __restrict__ A,
                                                 const u16* __restrict__ W,
                                                 const float* __restrict__ bias,
                                                 u16* __restrict__ out,
                                                 int clog2, int nslab, int K,
                                                 int relu) {
    __shared__ u16 As[2][128 * 32];
    __shared__ u16 Bs[2][64 * 32];
    int tid = threadIdx.x;
    int m0 = blockIdx.x * 128;
    int n0 = blockIdx.y * 64;
    int Cin = 1 << clog2;

    int r0 = tid >> 2;
    int q8 = (tid & 3) * 8;
    int arow0 = pbase(m0 + r0, clog2) + q8;
    int arow1 = pbase(m0 + r0 + 64, clog2) + q8;
    int brow0 = (n0 + r0) * K + q8;
    int l8 = tid * 8;

    f32x4 acc[4][2];
    #pragma unroll
    for (int i = 0; i < 4; ++i)
        #pragma unroll
        for (int j = 0; j < 2; ++j)
            acc[i][j] = (f32x4){0.f, 0.f, 0.f, 0.f};

    int wid = tid >> 6;
    int wm = (wid >> 1) * 64;
    int wn = (wid & 1) * 32;
    int lane = tid & 63;
    int lr = lane & 15;
    int lq = lane >> 4;

    int nk = K >> 5;
    auto stage = [&](int buf, int kt) {
        int sl = kt >> clog2;
        int win = kt & (Cin - 1);
        int soff = 0;
        if (nslab == 9) {
            int d3 = sl / 3;
            soff = (((d3 - 1) * SPW + (sl - d3 * 3 - 1))) << clog2;
        }
        glds16(A + arow0 + soff + win, &As[buf][l8]);
        glds16(A + arow1 + soff + win, &As[buf][2048 + l8]);
        glds16(W + brow0 + kt, &Bs[buf][l8]);
    };

    stage(0, 0);
    #pragma unroll 1
    for (int it = 0; it < nk; ++it) {
        __syncthreads();
        if (it + 1 < nk) stage((it + 1) & 1, (it + 1) << 5);
        const u16* as = As[it & 1];
        const u16* bs = Bs[it & 1];
        bf16x8 af[4], bfr[2];
        #pragma unroll
        for (int i = 0; i < 4; ++i)
            af[i] = *(const bf16x8*)&as[(wm + i * 16 + lr) * 32 + lq * 8];
        #pragma unroll
        for (int j = 0; j < 2; ++j)
            bfr[j] = *(const bf16x8*)&bs[(wn + j * 16 + lr) * 32 + lq * 8];
        #pragma unroll
        for (int i = 0; i < 4; ++i)
            #pragma unroll
            for (int j = 0; j < 2; ++j)
                acc[i][j] = __builtin_amdgcn_mfma_f32_16x16x32_bf16(af[i], bfr[j], acc[i][j], 0, 0, 0);
    }

    #pragma unroll
    for (int i = 0; i < 4; ++i) {
        #pragma unroll
        for (int r = 0; r < 4; ++r) {
            int ml = m0 + wm + i * 16 + lq * 4 + r;
            int ob = pbase(ml, 7);
            #pragma unroll
            for (int j = 0; j < 2; ++j) {
                int n = n0 + wn + j * 16 + lr;
                float v = acc[i][j][r] + bias[n];
                if (relu) v = fmaxf(v, 0.f);
                out[ob + n] = f2b(v);
            }
        }
    }
}

// ---------------------------------------------------------------- chain conv (dil=1, 128ch in, 128ch out, K=1152)
// v7: 128x128 tile (m97-proven geometry), 864 blocks. Doubles MFMA per
// barrier-drain (8->16/wave/iter) and halves staging per pixel (each A row
// staged ONCE, not once per nt). Plus chunk-XOR LDS swizzle (both-sides, rule
// #21: pre-swizzled global source + swizzled read) cutting the af ds_read_b128
// conflict 8-way -> ~4-way. All 4 B-fragments live in the existing
// frag-ordered W at stride jj*512. launch_bounds(256,4): acc 64 + frags 32 +
// addr ~= 115 VGPR (cap 128).
__global__ __launch_bounds__(256, 4) void chain_conv(const u16* __restrict__ A,
                                                     const u16* __restrict__ W,   // frag-ordered [2][36][2][2][512]
                                                     const float* __restrict__ bias,
                                                     const u16* __restrict__ idn,
                                                     u16* __restrict__ out,
                                                     int relu) {
    __shared__ u16 As[2][128 * 32];
    int tid = threadIdx.x;
    int wg = blockIdx.x;
    int mt = (wg & 7) * 108 + (wg >> 3);   // bijective: 864 = 8*108; 108 mt = 2 images per XCD
    int m0 = mt * 128;

    int r0 = tid >> 2;
    int c8 = ((tid & 3) ^ (r0 & 3)) * 8;   // pre-swizzled logical chunk for this lane
    int pbq[2];
    #pragma unroll
    for (int q = 0; q < 2; ++q) {
        int p = m0 + r0 + q * 64;
        int b = p / HW6912;
        int rem = p - b * HW6912;
        int y = rem / IMW;
        int x = rem - y * IMW;
        pbq[q] = ((b * SPH + y + 1) * SPW + (x + 1)) * 128;
    }
    int l8 = tid * 8;

    f32x4 acc[4][4];
    #pragma unroll
    for (int i = 0; i < 4; ++i)
        #pragma unroll
        for (int jj = 0; jj < 4; ++jj)
            acc[i][jj] = (f32x4){0.f, 0.f, 0.f, 0.f};

    int wid = tid >> 6;
    int wm = (wid >> 1) * 64;
    int wn2 = wid & 1;                 // n-half: 64 cols
    int lane = tid & 63;
    int lr = lane & 15;
    int lq = lane >> 4;
    int rchunk = (lq ^ (lr & 3)) * 8;  // swizzled read chunk (row&3 == lr&3)

    // fragment-ordered W base: fragments at + it*2048 + jj*512
    const u16* wv = W + wn2 * 73728 + lane * 8;

    auto stage = [&](int buf, int kt) {
        int sl = kt >> 7;           // tap 0..8
        int win = kt & 127;
        int d3 = sl / 3;
        int soff = ((d3 - 1) * SPW + (sl - d3 * 3 - 1)) * 128;
        glds16(A + pbq[0] + soff + win + c8, &As[buf][l8]);
        glds16(A + pbq[1] + soff + win + c8, &As[buf][2048 + l8]);
    };

    stage(0, 0);
    #pragma unroll 1
    for (int it = 0; it < 36; ++it) {
        __syncthreads();
        if (it + 1 < 36) stage((it + 1) & 1, (it + 1) << 5);
        const u16* as = As[it & 1];
        bf16x8 af[4], bfr[4];
        #pragma unroll
        for (int i = 0; i < 4; ++i)
            af[i] = *(const bf16x8*)&as[(wm + i * 16 + lr) * 32 + rchunk];
        #pragma unroll
        for (int jj = 0; jj < 4; ++jj)
            bfr[jj] = *(const bf16x8*)(wv + it * 2048 + jj * 512);
        #pragma unroll
        for (int i = 0; i < 4; ++i)
            #pragma unroll
            for (int jj = 0; jj < 4; ++jj)
                acc[i][jj] = __builtin_amdgcn_mfma_f32_16x16x32_bf16(af[i], bfr[jj], acc[i][jj], 0, 0, 0);
    }

    #pragma unroll
    for (int i = 0; i < 4; ++i) {
        #pragma unroll
        for (int r = 0; r < 4; ++r) {
            int ml = m0 + wm + i * 16 + lq * 4 + r;
            int ob = pbase(ml, 7);
            #pragma unroll
            for (int jj = 0; jj < 4; ++jj) {
                int n = wn2 * 64 + jj * 16 + lr;
                float v = acc[i][jj][r] + bias[n];
                if (idn) v += b2f(idn[ob + n]);
                if (relu) v = fmaxf(v, 0.f);
                out[ob + n] = f2b(v);
            }
        }
    }
}

// ---------------------------------------------------------------- offset conv (dilated, reads h1s with explicit zero-pad)
// v3: XCD-locality swizzle (27 mt per XCD, 8 nt-tiles adjacent).
__global__ __launch_bounds__(256, 8) void off_conv(const u16* __restrict__ A,   // h1s
                                                   const u16* __restrict__ W,   // frag-ordered [nt][it][w2][j][64*8]
                                                   u16* __restrict__ out,       // [m_local][468]
                                                   int dil, int m_base) {
    __shared__ u16 As[2][128 * 32];
    int tid = threadIdx.x;
    int wg = blockIdx.x;
    int sw = (wg & 7) * 216 + (wg >> 3);   // bijective: 1728 = 8*216
    int mt = sw >> 3, nt = sw & 7;
    int m0 = mt * 128, n0 = nt * 64;

    int r0 = tid >> 2;
    int q8 = (tid & 3) * 8;
    int pb2[2], py[2], px[2];
    #pragma unroll
    for (int q = 0; q < 2; ++q) {
        int p = m_base + m0 + r0 + q * 64;
        int b = p / HW6912;
        int rem = p - b * HW6912;
        pb2[q] = b;
        py[q] = rem / IMW;
        px[q] = rem - py[q] * IMW;
    }
    int l8 = tid * 8;

    f32x4 acc[4][2];
    #pragma unroll
    for (int i = 0; i < 4; ++i) {
        acc[i][0] = (f32x4){0.f, 0.f, 0.f, 0.f};
        acc[i][1] = (f32x4){0.f, 0.f, 0.f, 0.f};
    }

    int wid = tid >> 6;
    int wm = (wid >> 1) * 64;
    int wn = (wid & 1) * 32;
    int lane = tid & 63;
    int lr = lane & 15;
    int lq = lane >> 4;

    // fragment-ordered W base for this wave: + it*2048 + j*512 per fragment
    const u16* wv = W + nt * 73728 + (wid & 1) * 1024 + lane * 8;

    auto stage = [&](int buf, int kt) {
        int sl = kt >> 7;
        int win = kt & 127;
        int d3 = sl / 3;
        int dy = (d3 - 1) * dil, dx = (sl - d3 * 3 - 1) * dil;
        #pragma unroll
        for (int q = 0; q < 2; ++q) {
            int y2 = py[q] + dy, x2 = px[q] + dx;
            uint4 v = make_uint4(0u, 0u, 0u, 0u);
            if (y2 >= 0 && y2 < IMH && x2 >= 0 && x2 < IMW)
                v = *(const uint4*)(A + ((pb2[q] * SPH + y2 + 1) * SPW + x2 + 1) * 128 + win + q8);
            *(uint4*)&As[buf][q * 2048 + l8] = v;
        }
    };

    stage(0, 0);
    #pragma unroll 1
    for (int it = 0; it < 36; ++it) {
        __syncthreads();
        if (it + 1 < 36) stage((it + 1) & 1, (it + 1) << 5);
        const u16* as = As[it & 1];
        bf16x8 af[4], bfr[2];
        #pragma unroll
        for (int i = 0; i < 4; ++i)
            af[i] = *(const bf16x8*)&as[(wm + i * 16 + lr) * 32 + lq * 8];
        bfr[0] = *(const bf16x8*)(wv + it * 2048);
        bfr[1] = *(const bf16x8*)(wv + it * 2048 + 512);
        #pragma unroll
        for (int i = 0; i < 4; ++i)
            #pragma unroll
            for (int j = 0; j < 2; ++j)
                acc[i][j] = __builtin_amdgcn_mfma_f32_16x16x32_bf16(af[i], bfr[j], acc[i][j], 0, 0, 0);
    }

    #pragma unroll
    for (int i = 0; i < 4; ++i) {
        #pragma unroll
        for (int r = 0; r < 4; ++r) {
            int ml = m0 + wm + i * 16 + lq * 4 + r;
            int ob = ml * 468;
            #pragma unroll
            for (int j = 0; j < 2; ++j) {
                int n = n0 + wn + j * 16 + lr;
                if (n < 468) out[ob + n] = f2b(acc[i][j][r]);
            }
        }
    }
}

// ---------------------------------------------------------------- deformable conv
template <int F>
__device__ __forceinline__ float dsamp2(const void* sup, int base, int yi, int xi) {
    bool ok = (yi >= 0) & (yi < IMH) & (xi >= 0) & (xi < IMW);
    int yc = yi < 0 ? 0 : (yi > IMH - 1 ? IMH - 1 : yi);
    int xc = xi < 0 ? 0 : (xi > IMW - 1 ? IMW - 1 : xi);
    float v = F ? ((const float*)sup)[base + yc * IMW + xc]
                : b2f(((const u16*)sup)[base + yc * IMW + xc]);
    return ok ? v : 0.f;
}

template <int F>
__device__ __forceinline__ void deform_body(const void* __restrict__ sup,
                                            const u16* __restrict__ oc,
                                            const float* __restrict__ wsm,
                                            f32x4 acc[7],
                                            int c0, int c1, int b, int y, int x, int dil) {
    #pragma unroll 1
    for (int c = c0; c < c1; ++c) {
        int ibase = (b * CIN + c) * HW6912;
        #pragma unroll
        for (int t = 0; t < 9; ++t) {
            u32 pr = *(const u32*)(oc + c * 18 + t * 2);
            float dy = b2f((u16)(pr & 0xffffu));
            float dx = b2f((u16)(pr >> 16));
            float py = (float)(y + (t / 3 - 1) * dil) + dy;
            float px = (float)(x + (t % 3 - 1) * dil) + dx;
            float y0f = floorf(py), x0f = floorf(px);
            float ly = py - y0f, lx = px - x0f;
            int y0 = (int)y0f, x0 = (int)x0f;
            float v00 = dsamp2<F>(sup, ibase, y0, x0);
            float v01 = dsamp2<F>(sup, ibase, y0, x0 + 1);
            float v10 = dsamp2<F>(sup, ibase, y0 + 1, x0);
            float v11 = dsamp2<F>(sup, ibase, y0 + 1, x0 + 1);
            float val = (v00 * (1.f - lx) + v01 * lx) * (1.f - ly)
                      + (v10 * (1.f - lx) + v11 * lx) * ly;
            const float4* wr = (const float4*)&wsm[(c * 9 + t) * 28];
            #pragma unroll
            for (int u = 0; u < 7; ++u) {
                float4 w4 = wr[u];
                acc[u][0] = fmaf(val, w4.x, acc[u][0]);
                acc[u][1] = fmaf(val, w4.y, acc[u][1]);
                acc[u][2] = fmaf(val, w4.z, acc[u][2]);
                acc[u][3] = fmaf(val, w4.w, acc[u][3]);
            }
        }
    }
}

// v4 (R10-proven): 32px x 8cg, 864 blocks, XCD swizzle, no atomics;
// shfl_xor(32) pair-reduce + red[4][32][27]; coalesced wsm from prep_dw.
__global__ __launch_bounds__(256) void deform_kernel(const void* __restrict__ sup,
                                                     const u16* __restrict__ offb,
                                                     const float* __restrict__ wsp,
                                                     float* __restrict__ accws,
                                                     int dil, int first, int m_base,
                                                     const int* __restrict__ flag) {
    int f = *flag;
    __shared__ alignas(16) float wsm[26 * 9 * 28];
    __shared__ float red[4 * 32 * 27];
    int tid = threadIdx.x;
    int bid = blockIdx.x;
    int sw = (bid & 7) * 108 + (bid >> 3);   // bijective: 864 = 8*108
    for (int i = tid; i < 1638; i += 256)
        ((float4*)wsm)[i] = ((const float4*)wsp)[i];
    __syncthreads();

    int px = tid & 31;
    int cg = tid >> 5;                 // 0..7
    int c0 = (cg * 26) >> 3;
    int c1 = ((cg + 1) * 26) >> 3;
    int ml = sw * 32 + px;
    int m = m_base + ml;
    int b = m / HW6912;
    int p = m - b * HW6912;
    int y = p / IMW;
    int x = p - y * IMW;

    f32x4 acc[7];
    #pragma unroll
    for (int u = 0; u < 7; ++u) acc[u] = (f32x4){0.f, 0.f, 0.f, 0.f};

    const u16* oc = offb + (size_t)ml * 468;
    if (f) deform_body<1>(sup, oc, wsm, acc, c0, c1, b, y, x, dil);
    else   deform_body<0>(sup, oc, wsm, acc, c0, c1, b, y, x, dil);

    // in-wave pair-reduce: lane l <-> l^32 (same px, cg pair 2w/2w+1)
    #pragma unroll
    for (int u = 0; u < 7; ++u)
        #pragma unroll
        for (int k2 = 0; k2 < 4; ++k2) {
            float v = acc[u][k2];
            acc[u][k2] = v + __shfl_xor(v, 32);
        }

    int w = tid >> 6;                  // wave 0..3
    if (!(tid & 32)) {                 // lanes 0-31 of each wave hold the pair sum
        float* mr = red + (w * 32 + px) * 27;
        #pragma unroll
        for (int u = 0; u < 7; ++u)
            #pragma unroll
            for (int k2 = 0; k2 < 4; ++k2) {
                int o = u * 4 + k2;
                if (o < 26) mr[o] = acc[u][k2];
            }
    }
    __syncthreads();

    int base_m = m_base + sw * 32;
    for (int v = tid; v < 32 * 26; v += 256) {
        int ppx = v / 26;
        int o = v - ppx * 26;
        float s = red[(0 * 32 + ppx) * 27 + o] + red[(1 * 32 + ppx) * 27 + o]
                + red[(2 * 32 + ppx) * 27 + o] + red[(3 * 32 + ppx) * 27 + o];
        size_t ai = (size_t)(base_m + ppx) * 32 + o;
        if (first) accws[ai] = s;
        else       accws[ai] += s;
    }
}

// ---------------------------------------------------------------- finalize
__global__ __launch_bounds__(256) void finalize_kernel(const float* __restrict__ accws,
                                                       void* __restrict__ out,
                                                       const int* __restrict__ flag) {
    int f = *flag;
    int q = blockIdx.x * 256 + threadIdx.x;
    int b = q / (CIN * HW6912);
    int r = q - b * (CIN * HW6912);
    int o = r / HW6912;
    int p = r - o * HW6912;
    float v = accws[(size_t)(b * HW6912 + p) * 32 + o] * 0.2f;
    if (f) ((float*)out)[q] = v;
    else   ((u16*)out)[q] = f2b(v);
}

// ---------------------------------------------------------------- host
extern "C" void kernel_launch(void* const* d_in, const int* in_sizes, int n_in,
                              void* d_out, int out_size, void* d_ws, size_t ws_size,
                              hipStream_t stream) {
    (void)in_sizes; (void)n_in; (void)out_size;
    const void* ref_x    = d_in[0];
    const void* sup_x    = d_in[1];
    const void* w1_0     = d_in[2];
    const void* w2_0     = d_in[3];
    const void* wd_0     = d_in[4];
    const void* bn1_0    = d_in[5];
    const void* bn2_0    = d_in[6];
    const void* bnd_0    = d_in[7];
    const void* w1_rest  = d_in[8];
    const void* w2_rest  = d_in[9];
    const void* bn1_rest = d_in[10];
    const void* bn2_rest = d_in[11];
    const void* offset_w = d_in[12];
    const void* deform_w = d_in[13];

    // workspace layout (bytes)
    size_t o_x0    = 0;                          // 16*98*74*32*2   =  7,426,048
    size_t o_h0    = o_x0 + 7426048;             // 16*98*74*128*2  = 29,704,192 (offb aliases)
    size_t o_h1s   = o_h0 + 29704192;            // 29,704,192
    size_t o_acc   = o_h1s + 29704192;           // 14,155,776
    size_t o_wrest = o_acc + 14155776;           // 11,206,656
    size_t o_w20   = o_wrest + 11206656;         //    294,912
    size_t o_w10   = o_w20 + 294912;             //     73,728
    size_t o_wd    = o_w10 + 73728;              //      8,192
    size_t o_woff  = o_wd + 8192;                //  5,898,240
    size_t o_bias  = o_woff + 5898240;           //     20,992
    size_t o_wsall = o_bias + 20992;             //    131,072 (5*6552 floats)
    size_t o_flag  = o_wsall + 131072;           //         64
    size_t o_end   = o_flag + 64;                // 98,624,128
    if (ws_size < o_end) return;

    char* ws = (char*)d_ws;
    u16* x0    = (u16*)(ws + o_x0);
    u16* h0    = (u16*)(ws + o_h0);
    u16* offb  = (u16*)(ws + o_h0);      // alias: h0 dead once the chain finishes
    u16* h1s   = (u16*)(ws + o_h1s);
    float* accb = (float*)(ws + o_acc);
    u16* Wr    = (u16*)(ws + o_wrest);
    u16* W20   = (u16*)(ws + o_w20);
    u16* W10   = (u16*)(ws + o_w10);
    u16* Wd    = (u16*)(ws + o_wd);
    u16* Woff  = (u16*)(ws + o_woff);
    float* biasb = (float*)(ws + o_bias);
    float* wsall = (float*)(ws + o_wsall);
    int* flagp = (int*)(ws + o_flag);

    dim3 blk(256);

    probe_kernel<<<1, 64, 0, stream>>>(bn1_0, flagp);
    // zero x0 + h0 + h1s (padding halos must be zero)
    zero_ws_kernel<<<2048, blk, 0, stream>>>((uint4*)ws, (int)((7426048 + 2 * 29704192) / 16));
    fill_x0_kernel<<<432, blk, 0, stream>>>(ref_x, sup_x, x0, flagp);
    prep_rest_kernel<<<21888, blk, 0, stream>>>(w1_rest, w2_rest, bn1_rest, bn2_rest, Wr, flagp);
    prep_b0_kernel<<<736, blk, 0, stream>>>(w1_0, w2_0, wd_0, bn1_0, bn2_0, bnd_0, W20, W10, Wd, flagp);
    prep_off_kernel<<<11520, blk, 0, stream>>>(offset_w, Woff, flagp);
    prep_dw_kernel<<<128, blk, 0, stream>>>(deform_w, wsall, flagp);
    prep_bias_kernel<<<21, blk, 0, stream>>>(bn1_0, bn2_0, bnd_0, bn1_rest, bn2_rest, biasb, flagp);

    // block0: downsample (1x1 conv + BN) x0 -> h1s ; conv1 x0 -> h0
    conv_gemm<<<dim3(864, 2), blk, 0, stream>>>(x0, Wd, biasb + 2 * 128, h1s, 5, 1, 32, 0);
    conv_gemm<<<dim3(864, 2), blk, 0, stream>>>(x0, W10, biasb + 0 * 128, h0, 5, 9, 288, 1);
    // block0: conv2 + BN + idn(h1s) + relu -> h1s
    chain_conv<<<864, blk, 0, stream>>>(h0, W20, biasb + 1 * 128, h1s, h1s, 1);

    for (int t = 0; t < 19; ++t) {
        const u16* wa = Wr + (size_t)t * 147456;
        const u16* wb = Wr + (size_t)(19 + t) * 147456;
        chain_conv<<<864, blk, 0, stream>>>(h1s, wa, biasb + (3 + t) * 128, nullptr, h0, 1);
        chain_conv<<<864, blk, 0, stream>>>(h0, wb, biasb + (22 + t) * 128, h1s, h1s, 1);
    }

    // 5 dilation branches, chunked over 4 batches (offb aliases h0)
    const int dils[5] = {3, 6, 12, 18, 24};
    for (int i = 0; i < 5; ++i) {
        for (int cb = 0; cb < 4; ++cb) {
            int mb = cb * 27648;
            off_conv<<<1728, blk, 0, stream>>>(h1s, Woff + (size_t)i * 589824, offb, dils[i], mb);
            deform_kernel<<<864, blk, 0, stream>>>(sup_x, offb, wsall + (size_t)i * 6552,
                                                   accb, dils[i], (i == 0) ? 1 : 0, mb, flagp);
        }
    }
    finalize_kernel<<<11232, blk, 0, stream>>>(accb, d_out, flagp);
}

// Round 12
// 3650.227 us; speedup vs baseline: 1.7690x; 1.0200x over previous
//
#include <hip/hip_runtime.h>

typedef unsigned short u16;
typedef unsigned int u32;
typedef __bf16 bf16x8 __attribute__((ext_vector_type(8)));
typedef float f32x4 __attribute__((ext_vector_type(4)));

#define NB 16
#define CIN 26
#define IMH 96
#define IMW 72
#define HW6912 6912      // 96*72
#define NPIX 110592      // 16*6912
// small padded geom (all internal activations): 98 x 74, pad 1
#define SPH 98
#define SPW 74
#define SPAD 1

__device__ __forceinline__ float b2f(u16 h) {
    union { u32 u; float f; } x; x.u = ((u32)h) << 16; return x.f;
}
__device__ __forceinline__ u16 f2b(float f) {
    union { float f; u32 u; } x; x.f = f;
    u32 u = x.u;
    u32 r = (u + 0x7fffu + ((u >> 16) & 1u)) >> 16;
    return (u16)r;
}
__device__ __forceinline__ float ldin(const void* p, int i, int f) {
    return f ? ((const float*)p)[i] : b2f(((const u16*)p)[i]);
}

// map flat pixel m -> element offset in small padded NHWC buffer, (1<<clog2) ch
__device__ __forceinline__ int pbase(int m, int clog2) {
    int b = m / HW6912;
    int p = m - b * HW6912;
    int y = p / IMW;
    int x = p - y * IMW;
    return (((b * SPH + y + SPAD) * SPW) + (x + SPAD)) << clog2;
}

__device__ __forceinline__ void glds16(const u16* g, u16* l) {
    __builtin_amdgcn_global_load_lds(
        (const __attribute__((address_space(1))) void*)g,
        (__attribute__((address_space(3))) void*)l, 16, 0, 0);
}

// ---------------------------------------------------------------- dtype probe
__global__ void probe_kernel(const void* bn, int* flag) {
    if (threadIdx.x == 0 && blockIdx.x == 0) {
        const float* f = (const float*)bn;
        int cnt = 0;
        for (int j = 64; j < 128; ++j) {
            float v = f[j];
            if (v >= 0.4f && v <= 1.6f) cnt++;
        }
        *flag = (cnt >= 32) ? 1 : 0;
    }
}

// ---------------------------------------------------------------- zero
__global__ __launch_bounds__(256) void zero_ws_kernel(uint4* p, int n16) {
    int i = blockIdx.x * 256 + threadIdx.x;
    int stride = gridDim.x * 256;
    for (; i < n16; i += stride) p[i] = make_uint4(0u, 0u, 0u, 0u);
}

// ---------------------------------------------------------------- x0 = ref - sup -> small padded NHWC(32)
__global__ __launch_bounds__(256) void fill_x0_kernel(const void* __restrict__ ref,
                                                      const void* __restrict__ sup,
                                                      u16* __restrict__ x0,
                                                      const int* __restrict__ flag) {
    int f = *flag;
    int t = blockIdx.x * 256 + threadIdx.x;
    int b = t / HW6912;
    int p = t - b * HW6912;
    int y = p / IMW;
    int x = p - y * IMW;
    int dst = ((b * SPH + y + SPAD) * SPW + (x + SPAD)) << 5;
    #pragma unroll 1
    for (int c = 0; c < CIN; ++c) {
        int src = (b * CIN + c) * HW6912 + p;
        x0[dst + c] = f2b(ldin(ref, src, f) - ldin(sup, src, f));
    }
}

// ---------------------------------------------------------------- weight preps
// prep_rest v2: chain weights in MFMA-fragment order (harness-verified).
__global__ __launch_bounds__(256) void prep_rest_kernel(const void* __restrict__ w1r,
                                                        const void* __restrict__ w2r,
                                                        const void* __restrict__ bn1r,
                                                        const void* __restrict__ bn2r,
                                                        u16* __restrict__ dst,
                                                        const int* __restrict__ flag) {
    int f = *flag;
    int idx = blockIdx.x * 256 + threadIdx.x;        // 38*147456
    int c = idx / 147456;
    int e = idx - c * 147456;
    int ee = e & 7;
    int l = (e >> 3) & 63;
    int j = (e >> 9) & 1;
    int w2 = (e >> 10) & 1;
    int rest = e >> 11;            // 0..71
    int it = rest % 36;
    int nt = rest / 36;
    int n = nt * 64 + w2 * 32 + j * 16 + (l & 15);
    int k = it * 32 + ((l >> 4) << 3) + ee;
    int s = k >> 7, ci = k & 127;
    const void* w  = (c < 19) ? w1r : w2r;
    int wb         = ((c < 19) ? c : (c - 19)) * 147456;
    const void* bn = (c < 19) ? bn1r : bn2r;
    int bb         = ((c < 19) ? c : (c - 19)) * 512;
    float inv = ldin(bn, bb + n, f) * rsqrtf(ldin(bn, bb + 384 + n, f) + 1e-5f);
    dst[idx] = f2b(ldin(w, wb + (n * 128 + ci) * 9 + s, f) * inv);
}

__global__ __launch_bounds__(256) void prep_b0_kernel(const void* __restrict__ w1_0,
                                                      const void* __restrict__ w2_0,
                                                      const void* __restrict__ wd_0,
                                                      const void* __restrict__ bn1_0,
                                                      const void* __restrict__ bn2_0,
                                                      const void* __restrict__ bnd_0,
                                                      u16* __restrict__ W20,
                                                      u16* __restrict__ W10,
                                                      u16* __restrict__ Wd,
                                                      const int* __restrict__ flag) {
    int f = *flag;
    int idx = blockIdx.x * 256 + threadIdx.x;  // 188416
    if (idx < 147456) {
        // W20 in fragment order (for chain_conv)
        int e = idx;
        int ee = e & 7;
        int l = (e >> 3) & 63;
        int j = (e >> 9) & 1;
        int w2 = (e >> 10) & 1;
        int rest = e >> 11;
        int it = rest % 36;
        int nt = rest / 36;
        int n = nt * 64 + w2 * 32 + j * 16 + (l & 15);
        int k = it * 32 + ((l >> 4) << 3) + ee;
        int s = k >> 7, ci = k & 127;
        float inv = ldin(bn2_0, n, f) * rsqrtf(ldin(bn2_0, 384 + n, f) + 1e-5f);
        W20[idx] = f2b(ldin(w2_0, (n * 128 + ci) * 9 + s, f) * inv);
    } else if (idx < 184320) {
        int j = idx - 147456;
        int o = j / 288, k = j - o * 288;
        int s = k >> 5, ci = k & 31;
        float inv = ldin(bn1_0, o, f) * rsqrtf(ldin(bn1_0, 384 + o, f) + 1e-5f);
        W10[j] = (ci < CIN) ? f2b(ldin(w1_0, (o * CIN + ci) * 9 + s, f) * inv) : (u16)0;
    } else {
        int j = idx - 184320;
        int o = j >> 5, ci = j & 31;
        float inv = ldin(bnd_0, o, f) * rsqrtf(ldin(bnd_0, 384 + o, f) + 1e-5f);
        Wd[j] = (ci < CIN) ? f2b(ldin(wd_0, o * CIN + ci, f) * inv) : (u16)0;
    }
}

// prep_off v2: store W in MFMA-fragment order (B direct-to-VGPR in off_conv).
__global__ __launch_bounds__(256) void prep_off_kernel(const void* __restrict__ offw,
                                                       u16* __restrict__ dst,
                                                       const int* __restrict__ flag) {
    int f = *flag;
    int idx = blockIdx.x * 256 + threadIdx.x;    // 5*8*36*2*2*512 = 2,949,120
    int e = idx & 7;
    int l = (idx >> 3) & 63;
    int j = (idx >> 9) & 1;
    int w2 = (idx >> 10) & 1;
    int rest = idx >> 11;
    int it = rest % 36;
    int dnt = rest / 36;
    int nt = dnt & 7;
    int d = dnt >> 3;
    int n = nt * 64 + w2 * 32 + j * 16 + (l & 15);
    int k = it * 32 + (l >> 4) * 8 + e;
    int s = k >> 7, ci = k & 127;
    dst[idx] = (n < 468) ? f2b(ldin(offw, ((d * 468 + n) * 128 + ci) * 9 + s, f)) : (u16)0;
}

// prep_dw: deform weights -> [5][26ch c][9 tap][28 o-padded] float for
// coalesced float4 wsm staging (R8-proven: FETCH 26->14.7 MB).
__global__ __launch_bounds__(256) void prep_dw_kernel(const void* __restrict__ dwall,
                                                      float* __restrict__ dst,
                                                      const int* __restrict__ flag) {
    int f = *flag;
    int idx = blockIdx.x * 256 + threadIdx.x;    // 5*6552 = 32760
    if (idx >= 32760) return;
    int d = idx / 6552;
    int r = idx - d * 6552;
    int o = r % 28;
    int ct = r / 28;
    int c = ct / 9, t = ct - c * 9;
    dst[idx] = (o < CIN) ? ldin(dwall, d * 6084 + (o * CIN + c) * 9 + t, f) : 0.f;
}

__global__ __launch_bounds__(256) void prep_bias_kernel(const void* __restrict__ bn1_0,
                                                        const void* __restrict__ bn2_0,
                                                        const void* __restrict__ bnd_0,
                                                        const void* __restrict__ bn1r,
                                                        const void* __restrict__ bn2r,
                                                        float* __restrict__ dst,
                                                        const int* __restrict__ flag) {
    int f = *flag;
    int idx = blockIdx.x * 256 + threadIdx.x;
    if (idx >= 41 * 128) return;
    int set = idx >> 7;
    int o = idx & 127;
    const void* bn; int bb = 0;
    if (set == 0) bn = bn1_0;
    else if (set == 1) bn = bn2_0;
    else if (set == 2) bn = bnd_0;
    else if (set < 22) { bn = bn1r; bb = (set - 3) * 512; }
    else { bn = bn2r; bb = (set - 22) * 512; }
    float s = ldin(bn, bb + o, f), b = ldin(bn, bb + 128 + o, f);
    float mu = ldin(bn, bb + 256 + o, f), v = ldin(bn, bb + 384 + o, f);
    float inv = s * rsqrtf(v + 1e-5f);
    dst[idx] = b - mu * inv;
}

// ---------------------------------------------------------------- generic implicit-GEMM conv (R7 structure)
// Used only for the two cheap x0 convs (K=32 / K=288).
__global__ __launch_bounds__(256) void conv_gemm(const u16* __restrict__ A,
                                                 const u16* __restrict__ W,
                                                 const float* __restrict__ bias,
                                                 u16* __restrict__ out,
                                                 int clog2, int nslab, int K,
                                                 int relu) {
    __shared__ u16 As[2][128 * 32];
    __shared__ u16 Bs[2][64 * 32];
    int tid = threadIdx.x;
    int m0 = blockIdx.x * 128;
    int n0 = blockIdx.y * 64;
    int Cin = 1 << clog2;

    int r0 = tid >> 2;
    int q8 = (tid & 3) * 8;
    int arow0 = pbase(m0 + r0, clog2) + q8;
    int arow1 = pbase(m0 + r0 + 64, clog2) + q8;
    int brow0 = (n0 + r0) * K + q8;
    int l8 = tid * 8;

    f32x4 acc[4][2];
    #pragma unroll
    for (int i = 0; i < 4; ++i)
        #pragma unroll
        for (int j = 0; j < 2; ++j)
            acc[i][j] = (f32x4){0.f, 0.f, 0.f, 0.f};

    int wid = tid >> 6;
    int wm = (wid >> 1) * 64;
    int wn = (wid & 1) * 32;
    int lane = tid & 63;
    int lr = lane & 15;
    int lq = lane >> 4;

    int nk = K >> 5;
    auto stage = [&](int buf, int kt) {
        int sl = kt >> clog2;
        int win = kt & (Cin - 1);
        int soff = 0;
        if (nslab == 9) {
            int d3 = sl / 3;
            soff = (((d3 - 1) * SPW + (sl - d3 * 3 - 1))) << clog2;
        }
        glds16(A + arow0 + soff + win, &As[buf][l8]);
        glds16(A + arow1 + soff + win, &As[buf][2048 + l8]);
        glds16(W + brow0 + kt, &Bs[buf][l8]);
    };

    stage(0, 0);
    #pragma unroll 1
    for (int it = 0; it < nk; ++it) {
        __syncthreads();
        if (it + 1 < nk) stage((it + 1) & 1, (it + 1) << 5);
        const u16* as = As[it & 1];
        const u16* bs = Bs[it & 1];
        bf16x8 af[4], bfr[2];
        #pragma unroll
        for (int i = 0; i < 4; ++i)
            af[i] = *(const bf16x8*)&as[(wm + i * 16 + lr) * 32 + lq * 8];
        #pragma unroll
        for (int j = 0; j < 2; ++j)
            bfr[j] = *(const bf16x8*)&bs[(wn + j * 16 + lr) * 32 + lq * 8];
        #pragma unroll
        for (int i = 0; i < 4; ++i)
            #pragma unroll
            for (int j = 0; j < 2; ++j)
                acc[i][j] = __builtin_amdgcn_mfma_f32_16x16x32_bf16(af[i], bfr[j], acc[i][j], 0, 0, 0);
    }

    #pragma unroll
    for (int i = 0; i < 4; ++i) {
        #pragma unroll
        for (int r = 0; r < 4; ++r) {
            int ml = m0 + wm + i * 16 + lq * 4 + r;
            int ob = pbase(ml, 7);
            #pragma unroll
            for (int j = 0; j < 2; ++j) {
                int n = n0 + wn + j * 16 + lr;
                float v = acc[i][j][r] + bias[n];
                if (relu) v = fmaxf(v, 0.f);
                out[ob + n] = f2b(v);
            }
        }
    }
}

// ---------------------------------------------------------------- chain conv (dil=1, 128ch in, 128ch out, K=1152)
// v8: 128x128 tile + BK=64. R11 cycle model: ~1280 cyc/block-iter vs ~350 cyc
// of compute -> the per-iteration barrier + staging-latency drain (~L2 latency)
// is the critical path. BK 32->64 halves the iterations (36->18): each barrier
// drain now covers 32 MFMA/wave instead of 16, paying the ~450-cyc tax half as
// often. LDS 16->32 KB (As[2 bufs][2 halves][128*32]); launch_bounds(256,4)
// still 4 blocks/CU capacity >= the 3.375 the 864-grid supplies. Same proven
// c8/rchunk chunk-XOR swizzle per 32-half (R11-verified, conflicts halved).
__global__ __launch_bounds__(256, 4) void chain_conv(const u16* __restrict__ A,
                                                     const u16* __restrict__ W,   // frag-ordered [2][36][2][2][512]
                                                     const float* __restrict__ bias,
                                                     const u16* __restrict__ idn,
                                                     u16* __restrict__ out,
                                                     int relu) {
    __shared__ u16 As[2][2][128 * 32];   // [buf][k-half][row*32] = 32 KB
    int tid = threadIdx.x;
    int wg = blockIdx.x;
    int mt = (wg & 7) * 108 + (wg >> 3);   // bijective: 864 = 8*108; 108 mt = 2 images per XCD
    int m0 = mt * 128;

    int r0 = tid >> 2;
    int c8 = ((tid & 3) ^ (r0 & 3)) * 8;   // pre-swizzled logical chunk for this lane
    int pbq[2];
    #pragma unroll
    for (int q = 0; q < 2; ++q) {
        int p = m0 + r0 + q * 64;
        int b = p / HW6912;
        int rem = p - b * HW6912;
        int y = rem / IMW;
        int x = rem - y * IMW;
        pbq[q] = ((b * SPH + y + 1) * SPW + (x + 1)) * 128;
    }
    int l8 = tid * 8;

    f32x4 acc[4][4];
    #pragma unroll
    for (int i = 0; i < 4; ++i)
        #pragma unroll
        for (int jj = 0; jj < 4; ++jj)
            acc[i][jj] = (f32x4){0.f, 0.f, 0.f, 0.f};

    int wid = tid >> 6;
    int wm = (wid >> 1) * 64;
    int wn2 = wid & 1;                 // n-half: 64 cols
    int lane = tid & 63;
    int lr = lane & 15;
    int lq = lane >> 4;
    int rchunk = (lq ^ (lr & 3)) * 8;  // swizzled read chunk (row&3 == lr&3)

    // fragment-ordered W base: fragments at + it36*2048 + jj*512
    const u16* wv = W + wn2 * 73728 + lane * 8;

    auto stage = [&](int buf, int it2) {   // it2 = BK64 iteration index
        #pragma unroll
        for (int h = 0; h < 2; ++h) {
            int kt = (it2 * 2 + h) << 5;
            int sl = kt >> 7;           // tap 0..8
            int win = kt & 127;
            int d3 = sl / 3;
            int soff = ((d3 - 1) * SPW + (sl - d3 * 3 - 1)) * 128;
            glds16(A + pbq[0] + soff + win + c8, &As[buf][h][l8]);
            glds16(A + pbq[1] + soff + win + c8, &As[buf][h][2048 + l8]);
        }
    };

    stage(0, 0);
    #pragma unroll 1
    for (int it = 0; it < 18; ++it) {
        __syncthreads();
        if (it + 1 < 18) stage((it + 1) & 1, it + 1);
        #pragma unroll
        for (int kc = 0; kc < 2; ++kc) {
            const u16* as = As[it & 1][kc];
            int it36 = it * 2 + kc;
            bf16x8 af[4], bfr[4];
            #pragma unroll
            for (int i = 0; i < 4; ++i)
                af[i] = *(const bf16x8*)&as[(wm + i * 16 + lr) * 32 + rchunk];
            #pragma unroll
            for (int jj = 0; jj < 4; ++jj)
                bfr[jj] = *(const bf16x8*)(wv + it36 * 2048 + jj * 512);
            #pragma unroll
            for (int i = 0; i < 4; ++i)
                #pragma unroll
                for (int jj = 0; jj < 4; ++jj)
                    acc[i][jj] = __builtin_amdgcn_mfma_f32_16x16x32_bf16(af[i], bfr[jj], acc[i][jj], 0, 0, 0);
        }
    }

    #pragma unroll
    for (int i = 0; i < 4; ++i) {
        #pragma unroll
        for (int r = 0; r < 4; ++r) {
            int ml = m0 + wm + i * 16 + lq * 4 + r;
            int ob = pbase(ml, 7);
            #pragma unroll
            for (int jj = 0; jj < 4; ++jj) {
                int n = wn2 * 64 + jj * 16 + lr;
                float v = acc[i][jj][r] + bias[n];
                if (idn) v += b2f(idn[ob + n]);
                if (relu) v = fmaxf(v, 0.f);
                out[ob + n] = f2b(v);
            }
        }
    }
}

// ---------------------------------------------------------------- offset conv (dilated, reads h1s with explicit zero-pad)
// v3: XCD-locality swizzle (27 mt per XCD, 8 nt-tiles adjacent).
__global__ __launch_bounds__(256, 8) void off_conv(const u16* __restrict__ A,   // h1s
                                                   const u16* __restrict__ W,   // frag-ordered [nt][it][w2][j][64*8]
                                                   u16* __restrict__ out,       // [m_local][468]
                                                   int dil, int m_base) {
    __shared__ u16 As[2][128 * 32];
    int tid = threadIdx.x;
    int wg = blockIdx.x;
    int sw = (wg & 7) * 216 + (wg >> 3);   // bijective: 1728 = 8*216
    int mt = sw >> 3, nt = sw & 7;
    int m0 = mt * 128, n0 = nt * 64;

    int r0 = tid >> 2;
    int q8 = (tid & 3) * 8;
    int pb2[2], py[2], px[2];
    #pragma unroll
    for (int q = 0; q < 2; ++q) {
        int p = m_base + m0 + r0 + q * 64;
        int b = p / HW6912;
        int rem = p - b * HW6912;
        pb2[q] = b;
        py[q] = rem / IMW;
        px[q] = rem - py[q] * IMW;
    }
    int l8 = tid * 8;

    f32x4 acc[4][2];
    #pragma unroll
    for (int i = 0; i < 4; ++i) {
        acc[i][0] = (f32x4){0.f, 0.f, 0.f, 0.f};
        acc[i][1] = (f32x4){0.f, 0.f, 0.f, 0.f};
    }

    int wid = tid >> 6;
    int wm = (wid >> 1) * 64;
    int wn = (wid & 1) * 32;
    int lane = tid & 63;
    int lr = lane & 15;
    int lq = lane >> 4;

    // fragment-ordered W base for this wave: + it*2048 + j*512 per fragment
    const u16* wv = W + nt * 73728 + (wid & 1) * 1024 + lane * 8;

    auto stage = [&](int buf, int kt) {
        int sl = kt >> 7;
        int win = kt & 127;
        int d3 = sl / 3;
        int dy = (d3 - 1) * dil, dx = (sl - d3 * 3 - 1) * dil;
        #pragma unroll
        for (int q = 0; q < 2; ++q) {
            int y2 = py[q] + dy, x2 = px[q] + dx;
            uint4 v = make_uint4(0u, 0u, 0u, 0u);
            if (y2 >= 0 && y2 < IMH && x2 >= 0 && x2 < IMW)
                v = *(const uint4*)(A + ((pb2[q] * SPH + y2 + 1) * SPW + x2 + 1) * 128 + win + q8);
            *(uint4*)&As[buf][q * 2048 + l8] = v;
        }
    };

    stage(0, 0);
    #pragma unroll 1
    for (int it = 0; it < 36; ++it) {
        __syncthreads();
        if (it + 1 < 36) stage((it + 1) & 1, (it + 1) << 5);
        const u16* as = As[it & 1];
        bf16x8 af[4], bfr[2];
        #pragma unroll
        for (int i = 0; i < 4; ++i)
            af[i] = *(const bf16x8*)&as[(wm + i * 16 + lr) * 32 + lq * 8];
        bfr[0] = *(const bf16x8*)(wv + it * 2048);
        bfr[1] = *(const bf16x8*)(wv + it * 2048 + 512);
        #pragma unroll
        for (int i = 0; i < 4; ++i)
            #pragma unroll
            for (int j = 0; j < 2; ++j)
                acc[i][j] = __builtin_amdgcn_mfma_f32_16x16x32_bf16(af[i], bfr[j], acc[i][j], 0, 0, 0);
    }

    #pragma unroll
    for (int i = 0; i < 4; ++i) {
        #pragma unroll
        for (int r = 0; r < 4; ++r) {
            int ml = m0 + wm + i * 16 + lq * 4 + r;
            int ob = ml * 468;
            #pragma unroll
            for (int j = 0; j < 2; ++j) {
                int n = n0 + wn + j * 16 + lr;
                if (n < 468) out[ob + n] = f2b(acc[i][j][r]);
            }
        }
    }
}

// ---------------------------------------------------------------- deformable conv
template <int F>
__device__ __forceinline__ float dsamp2(const void* sup, int base, int yi, int xi) {
    bool ok = (yi >= 0) & (yi < IMH) & (xi >= 0) & (xi < IMW);
    int yc = yi < 0 ? 0 : (yi > IMH - 1 ? IMH - 1 : yi);
    int xc = xi < 0 ? 0 : (xi > IMW - 1 ? IMW - 1 : xi);
    float v = F ? ((const float*)sup)[base + yc * IMW + xc]
                : b2f(((const u16*)sup)[base + yc * IMW + xc]);
    return ok ? v : 0.f;
}

template <int F>
__device__ __forceinline__ void deform_body(const void* __restrict__ sup,
                                            const u16* __restrict__ oc,
                                            const float* __restrict__ wsm,
                                            f32x4 acc[7],
                                            int c0, int c1, int b, int y, int x, int dil) {
    #pragma unroll 1
    for (int c = c0; c < c1; ++c) {
        int ibase = (b * CIN + c) * HW6912;
        #pragma unroll
        for (int t = 0; t < 9; ++t) {
            u32 pr = *(const u32*)(oc + c * 18 + t * 2);
            float dy = b2f((u16)(pr & 0xffffu));
            float dx = b2f((u16)(pr >> 16));
            float py = (float)(y + (t / 3 - 1) * dil) + dy;
            float px = (float)(x + (t % 3 - 1) * dil) + dx;
            float y0f = floorf(py), x0f = floorf(px);
            float ly = py - y0f, lx = px - x0f;
            int y0 = (int)y0f, x0 = (int)x0f;
            float v00 = dsamp2<F>(sup, ibase, y0, x0);
            float v01 = dsamp2<F>(sup, ibase, y0, x0 + 1);
            float v10 = dsamp2<F>(sup, ibase, y0 + 1, x0);
            float v11 = dsamp2<F>(sup, ibase, y0 + 1, x0 + 1);
            float val = (v00 * (1.f - lx) + v01 * lx) * (1.f - ly)
                      + (v10 * (1.f - lx) + v11 * lx) * ly;
            const float4* wr = (const float4*)&wsm[(c * 9 + t) * 28];
            #pragma unroll
            for (int u = 0; u < 7; ++u) {
                float4 w4 = wr[u];
                acc[u][0] = fmaf(val, w4.x, acc[u][0]);
                acc[u][1] = fmaf(val, w4.y, acc[u][1]);
                acc[u][2] = fmaf(val, w4.z, acc[u][2]);
                acc[u][3] = fmaf(val, w4.w, acc[u][3]);
            }
        }
    }
}

// v4 (R10-proven): 32px x 8cg, 864 blocks, XCD swizzle, no atomics;
// shfl_xor(32) pair-reduce + red[4][32][27]; coalesced wsm from prep_dw.
__global__ __launch_bounds__(256) void deform_kernel(const void* __restrict__ sup,
                                                     const u16* __restrict__ offb,
                                                     const float* __restrict__ wsp,
                                                     float* __restrict__ accws,
                                                     int dil, int first, int m_base,
                                                     const int* __restrict__ flag) {
    int f = *flag;
    __shared__ alignas(16) float wsm[26 * 9 * 28];
    __shared__ float red[4 * 32 * 27];
    int tid = threadIdx.x;
    int bid = blockIdx.x;
    int sw = (bid & 7) * 108 + (bid >> 3);   // bijective: 864 = 8*108
    for (int i = tid; i < 1638; i += 256)
        ((float4*)wsm)[i] = ((const float4*)wsp)[i];
    __syncthreads();

    int px = tid & 31;
    int cg = tid >> 5;                 // 0..7
    int c0 = (cg * 26) >> 3;
    int c1 = ((cg + 1) * 26) >> 3;
    int ml = sw * 32 + px;
    int m = m_base + ml;
    int b = m / HW6912;
    int p = m - b * HW6912;
    int y = p / IMW;
    int x = p - y * IMW;

    f32x4 acc[7];
    #pragma unroll
    for (int u = 0; u < 7; ++u) acc[u] = (f32x4){0.f, 0.f, 0.f, 0.f};

    const u16* oc = offb + (size_t)ml * 468;
    if (f) deform_body<1>(sup, oc, wsm, acc, c0, c1, b, y, x, dil);
    else   deform_body<0>(sup, oc, wsm, acc, c0, c1, b, y, x, dil);

    // in-wave pair-reduce: lane l <-> l^32 (same px, cg pair 2w/2w+1)
    #pragma unroll
    for (int u = 0; u < 7; ++u)
        #pragma unroll
        for (int k2 = 0; k2 < 4; ++k2) {
            float v = acc[u][k2];
            acc[u][k2] = v + __shfl_xor(v, 32);
        }

    int w = tid >> 6;                  // wave 0..3
    if (!(tid & 32)) {                 // lanes 0-31 of each wave hold the pair sum
        float* mr = red + (w * 32 + px) * 27;
        #pragma unroll
        for (int u = 0; u < 7; ++u)
            #pragma unroll
            for (int k2 = 0; k2 < 4; ++k2) {
                int o = u * 4 + k2;
                if (o < 26) mr[o] = acc[u][k2];
            }
    }
    __syncthreads();

    int base_m = m_base + sw * 32;
    for (int v = tid; v < 32 * 26; v += 256) {
        int ppx = v / 26;
        int o = v - ppx * 26;
        float s = red[(0 * 32 + ppx) * 27 + o] + red[(1 * 32 + ppx) * 27 + o]
                + red[(2 * 32 + ppx) * 27 + o] + red[(3 * 32 + ppx) * 27 + o];
        size_t ai = (size_t)(base_m + ppx) * 32 + o;
        if (first) accws[ai] = s;
        else       accws[ai] += s;
    }
}

// ---------------------------------------------------------------- finalize
__global__ __launch_bounds__(256) void finalize_kernel(const float* __restrict__ accws,
                                                       void* __restrict__ out,
                                                       const int* __restrict__ flag) {
    int f = *flag;
    int q = blockIdx.x * 256 + threadIdx.x;
    int b = q / (CIN * HW6912);
    int r = q - b * (CIN * HW6912);
    int o = r / HW6912;
    int p = r - o * HW6912;
    float v = accws[(size_t)(b * HW6912 + p) * 32 + o] * 0.2f;
    if (f) ((float*)out)[q] = v;
    else   ((u16*)out)[q] = f2b(v);
}

// ---------------------------------------------------------------- host
extern "C" void kernel_launch(void* const* d_in, const int* in_sizes, int n_in,
                              void* d_out, int out_size, void* d_ws, size_t ws_size,
                              hipStream_t stream) {
    (void)in_sizes; (void)n_in; (void)out_size;
    const void* ref_x    = d_in[0];
    const void* sup_x    = d_in[1];
    const void* w1_0     = d_in[2];
    const void* w2_0     = d_in[3];
    const void* wd_0     = d_in[4];
    const void* bn1_0    = d_in[5];
    const void* bn2_0    = d_in[6];
    const void* bnd_0    = d_in[7];
    const void* w1_rest  = d_in[8];
    const void* w2_rest  = d_in[9];
    const void* bn1_rest = d_in[10];
    const void* bn2_rest = d_in[11];
    const void* offset_w = d_in[12];
    const void* deform_w = d_in[13];

    // workspace layout (bytes)
    size_t o_x0    = 0;                          // 16*98*74*32*2   =  7,426,048
    size_t o_h0    = o_x0 + 7426048;             // 16*98*74*128*2  = 29,704,192 (offb aliases)
    size_t o_h1s   = o_h0 + 29704192;            // 29,704,192
    size_t o_acc   = o_h1s + 29704192;           // 14,155,776
    size_t o_wrest = o_acc + 14155776;           // 11,206,656
    size_t o_w20   = o_wrest + 11206656;         //    294,912
    size_t o_w10   = o_w20 + 294912;             //     73,728
    size_t o_wd    = o_w10 + 73728;              //      8,192
    size_t o_woff  = o_wd + 8192;                //  5,898,240
    size_t o_bias  = o_woff + 5898240;           //     20,992
    size_t o_wsall = o_bias + 20992;             //    131,072 (5*6552 floats)
    size_t o_flag  = o_wsall + 131072;           //         64
    size_t o_end   = o_flag + 64;                // 98,624,128
    if (ws_size < o_end) return;

    char* ws = (char*)d_ws;
    u16* x0    = (u16*)(ws + o_x0);
    u16* h0    = (u16*)(ws + o_h0);
    u16* offb  = (u16*)(ws + o_h0);      // alias: h0 dead once the chain finishes
    u16* h1s   = (u16*)(ws + o_h1s);
    float* accb = (float*)(ws + o_acc);
    u16* Wr    = (u16*)(ws + o_wrest);
    u16* W20   = (u16*)(ws + o_w20);
    u16* W10   = (u16*)(ws + o_w10);
    u16* Wd    = (u16*)(ws + o_wd);
    u16* Woff  = (u16*)(ws + o_woff);
    float* biasb = (float*)(ws + o_bias);
    float* wsall = (float*)(ws + o_wsall);
    int* flagp = (int*)(ws + o_flag);

    dim3 blk(256);

    probe_kernel<<<1, 64, 0, stream>>>(bn1_0, flagp);
    // zero x0 + h0 + h1s (padding halos must be zero)
    zero_ws_kernel<<<2048, blk, 0, stream>>>((uint4*)ws, (int)((7426048 + 2 * 29704192) / 16));
    fill_x0_kernel<<<432, blk, 0, stream>>>(ref_x, sup_x, x0, flagp);
    prep_rest_kernel<<<21888, blk, 0, stream>>>(w1_rest, w2_rest, bn1_rest, bn2_rest, Wr, flagp);
    prep_b0_kernel<<<736, blk, 0, stream>>>(w1_0, w2_0, wd_0, bn1_0, bn2_0, bnd_0, W20, W10, Wd, flagp);
    prep_off_kernel<<<11520, blk, 0, stream>>>(offset_w, Woff, flagp);
    prep_dw_kernel<<<128, blk, 0, stream>>>(deform_w, wsall, flagp);
    prep_bias_kernel<<<21, blk, 0, stream>>>(bn1_0, bn2_0, bnd_0, bn1_rest, bn2_rest, biasb, flagp);

    // block0: downsample (1x1 conv + BN) x0 -> h1s ; conv1 x0 -> h0
    conv_gemm<<<dim3(864, 2), blk, 0, stream>>>(x0, Wd, biasb + 2 * 128, h1s, 5, 1, 32, 0);
    conv_gemm<<<dim3(864, 2), blk, 0, stream>>>(x0, W10, biasb + 0 * 128, h0, 5, 9, 288, 1);
    // block0: conv2 + BN + idn(h1s) + relu -> h1s
    chain_conv<<<864, blk, 0, stream>>>(h0, W20, biasb + 1 * 128, h1s, h1s, 1);

    for (int t = 0; t < 19; ++t) {
        const u16* wa = Wr + (size_t)t * 147456;
        const u16* wb = Wr + (size_t)(19 + t) * 147456;
        chain_conv<<<864, blk, 0, stream>>>(h1s, wa, biasb + (3 + t) * 128, nullptr, h0, 1);
        chain_conv<<<864, blk, 0, stream>>>(h0, wb, biasb + (22 + t) * 128, h1s, h1s, 1);
    }

    // 5 dilation branches, chunked over 4 batches (offb aliases h0)
    const int dils[5] = {3, 6, 12, 18, 24};
    for (int i = 0; i < 5; ++i) {
        for (int cb = 0; cb < 4; ++cb) {
            int mb = cb * 27648;
            off_conv<<<1728, blk, 0, stream>>>(h1s, Woff + (size_t)i * 589824, offb, dils[i], mb);
            deform_kernel<<<864, blk, 0, stream>>>(sup_x, offb, wsall + (size_t)i * 6552,
                                                   accb, dils[i], (i == 0) ? 1 : 0, mb, flagp);
        }
    }
    finalize_kernel<<<11232, blk, 0, stream>>>(accb, d_out, flagp);
}

// Round 13
// 3583.200 us; speedup vs baseline: 1.8021x; 1.0187x over previous
//
#include <hip/hip_runtime.h>

typedef unsigned short u16;
typedef unsigned int u32;
typedef __bf16 bf16x8 __attribute__((ext_vector_type(8)));
typedef float f32x4 __attribute__((ext_vector_type(4)));

#define NB 16
#define CIN 26
#define IMH 96
#define IMW 72
#define HW6912 6912      // 96*72
#define NPIX 110592      // 16*6912
// small padded geom (all internal activations): 98 x 74, pad 1
#define SPH 98
#define SPW 74
#define SPAD 1

__device__ __forceinline__ float b2f(u16 h) {
    union { u32 u; float f; } x; x.u = ((u32)h) << 16; return x.f;
}
__device__ __forceinline__ u16 f2b(float f) {
    union { float f; u32 u; } x; x.f = f;
    u32 u = x.u;
    u32 r = (u + 0x7fffu + ((u >> 16) & 1u)) >> 16;
    return (u16)r;
}
__device__ __forceinline__ float ldin(const void* p, int i, int f) {
    return f ? ((const float*)p)[i] : b2f(((const u16*)p)[i]);
}

// map flat pixel m -> element offset in small padded NHWC buffer, (1<<clog2) ch
__device__ __forceinline__ int pbase(int m, int clog2) {
    int b = m / HW6912;
    int p = m - b * HW6912;
    int y = p / IMW;
    int x = p - y * IMW;
    return (((b * SPH + y + SPAD) * SPW) + (x + SPAD)) << clog2;
}

__device__ __forceinline__ void glds16(const u16* g, u16* l) {
    __builtin_amdgcn_global_load_lds(
        (const __attribute__((address_space(1))) void*)g,
        (__attribute__((address_space(3))) void*)l, 16, 0, 0);
}

// ---------------------------------------------------------------- dtype probe
__global__ void probe_kernel(const void* bn, int* flag) {
    if (threadIdx.x == 0 && blockIdx.x == 0) {
        const float* f = (const float*)bn;
        int cnt = 0;
        for (int j = 64; j < 128; ++j) {
            float v = f[j];
            if (v >= 0.4f && v <= 1.6f) cnt++;
        }
        *flag = (cnt >= 32) ? 1 : 0;
    }
}

// ---------------------------------------------------------------- zero
__global__ __launch_bounds__(256) void zero_ws_kernel(uint4* p, int n16) {
    int i = blockIdx.x * 256 + threadIdx.x;
    int stride = gridDim.x * 256;
    for (; i < n16; i += stride) p[i] = make_uint4(0u, 0u, 0u, 0u);
}

// ---------------------------------------------------------------- x0 = ref - sup -> small padded NHWC(32)
__global__ __launch_bounds__(256) void fill_x0_kernel(const void* __restrict__ ref,
                                                      const void* __restrict__ sup,
                                                      u16* __restrict__ x0,
                                                      const int* __restrict__ flag) {
    int f = *flag;
    int t = blockIdx.x * 256 + threadIdx.x;
    int b = t / HW6912;
    int p = t - b * HW6912;
    int y = p / IMW;
    int x = p - y * IMW;
    int dst = ((b * SPH + y + SPAD) * SPW + (x + SPAD)) << 5;
    #pragma unroll 1
    for (int c = 0; c < CIN; ++c) {
        int src = (b * CIN + c) * HW6912 + p;
        x0[dst + c] = f2b(ldin(ref, src, f) - ldin(sup, src, f));
    }
}

// ---------------------------------------------------------------- weight preps
// prep_rest v2: chain weights in MFMA-fragment order (harness-verified).
__global__ __launch_bounds__(256) void prep_rest_kernel(const void* __restrict__ w1r,
                                                        const void* __restrict__ w2r,
                                                        const void* __restrict__ bn1r,
                                                        const void* __restrict__ bn2r,
                                                        u16* __restrict__ dst,
                                                        const int* __restrict__ flag) {
    int f = *flag;
    int idx = blockIdx.x * 256 + threadIdx.x;        // 38*147456
    int c = idx / 147456;
    int e = idx - c * 147456;
    int ee = e & 7;
    int l = (e >> 3) & 63;
    int j = (e >> 9) & 1;
    int w2 = (e >> 10) & 1;
    int rest = e >> 11;            // 0..71
    int it = rest % 36;
    int nt = rest / 36;
    int n = nt * 64 + w2 * 32 + j * 16 + (l & 15);
    int k = it * 32 + ((l >> 4) << 3) + ee;
    int s = k >> 7, ci = k & 127;
    const void* w  = (c < 19) ? w1r : w2r;
    int wb         = ((c < 19) ? c : (c - 19)) * 147456;
    const void* bn = (c < 19) ? bn1r : bn2r;
    int bb         = ((c < 19) ? c : (c - 19)) * 512;
    float inv = ldin(bn, bb + n, f) * rsqrtf(ldin(bn, bb + 384 + n, f) + 1e-5f);
    dst[idx] = f2b(ldin(w, wb + (n * 128 + ci) * 9 + s, f) * inv);
}

__global__ __launch_bounds__(256) void prep_b0_kernel(const void* __restrict__ w1_0,
                                                      const void* __restrict__ w2_0,
                                                      const void* __restrict__ wd_0,
                                                      const void* __restrict__ bn1_0,
                                                      const void* __restrict__ bn2_0,
                                                      const void* __restrict__ bnd_0,
                                                      u16* __restrict__ W20,
                                                      u16* __restrict__ W10,
                                                      u16* __restrict__ Wd,
                                                      const int* __restrict__ flag) {
    int f = *flag;
    int idx = blockIdx.x * 256 + threadIdx.x;  // 188416
    if (idx < 147456) {
        // W20 in fragment order (for chain_conv)
        int e = idx;
        int ee = e & 7;
        int l = (e >> 3) & 63;
        int j = (e >> 9) & 1;
        int w2 = (e >> 10) & 1;
        int rest = e >> 11;
        int it = rest % 36;
        int nt = rest / 36;
        int n = nt * 64 + w2 * 32 + j * 16 + (l & 15);
        int k = it * 32 + ((l >> 4) << 3) + ee;
        int s = k >> 7, ci = k & 127;
        float inv = ldin(bn2_0, n, f) * rsqrtf(ldin(bn2_0, 384 + n, f) + 1e-5f);
        W20[idx] = f2b(ldin(w2_0, (n * 128 + ci) * 9 + s, f) * inv);
    } else if (idx < 184320) {
        int j = idx - 147456;
        int o = j / 288, k = j - o * 288;
        int s = k >> 5, ci = k & 31;
        float inv = ldin(bn1_0, o, f) * rsqrtf(ldin(bn1_0, 384 + o, f) + 1e-5f);
        W10[j] = (ci < CIN) ? f2b(ldin(w1_0, (o * CIN + ci) * 9 + s, f) * inv) : (u16)0;
    } else {
        int j = idx - 184320;
        int o = j >> 5, ci = j & 31;
        float inv = ldin(bnd_0, o, f) * rsqrtf(ldin(bnd_0, 384 + o, f) + 1e-5f);
        Wd[j] = (ci < CIN) ? f2b(ldin(wd_0, o * CIN + ci, f) * inv) : (u16)0;
    }
}

// prep_off v2: store W in MFMA-fragment order (B direct-to-VGPR in off_conv).
__global__ __launch_bounds__(256) void prep_off_kernel(const void* __restrict__ offw,
                                                       u16* __restrict__ dst,
                                                       const int* __restrict__ flag) {
    int f = *flag;
    int idx = blockIdx.x * 256 + threadIdx.x;    // 5*8*36*2*2*512 = 2,949,120
    int e = idx & 7;
    int l = (idx >> 3) & 63;
    int j = (idx >> 9) & 1;
    int w2 = (idx >> 10) & 1;
    int rest = idx >> 11;
    int it = rest % 36;
    int dnt = rest / 36;
    int nt = dnt & 7;
    int d = dnt >> 3;
    int n = nt * 64 + w2 * 32 + j * 16 + (l & 15);
    int k = it * 32 + (l >> 4) * 8 + e;
    int s = k >> 7, ci = k & 127;
    dst[idx] = (n < 468) ? f2b(ldin(offw, ((d * 468 + n) * 128 + ci) * 9 + s, f)) : (u16)0;
}

// prep_dw: deform weights -> [5][26ch c][9 tap][28 o-padded] float for
// coalesced float4 wsm staging (R8-proven: FETCH 26->14.7 MB).
__global__ __launch_bounds__(256) void prep_dw_kernel(const void* __restrict__ dwall,
                                                      float* __restrict__ dst,
                                                      const int* __restrict__ flag) {
    int f = *flag;
    int idx = blockIdx.x * 256 + threadIdx.x;    // 5*6552 = 32760
    if (idx >= 32760) return;
    int d = idx / 6552;
    int r = idx - d * 6552;
    int o = r % 28;
    int ct = r / 28;
    int c = ct / 9, t = ct - c * 9;
    dst[idx] = (o < CIN) ? ldin(dwall, d * 6084 + (o * CIN + c) * 9 + t, f) : 0.f;
}

__global__ __launch_bounds__(256) void prep_bias_kernel(const void* __restrict__ bn1_0,
                                                        const void* __restrict__ bn2_0,
                                                        const void* __restrict__ bnd_0,
                                                        const void* __restrict__ bn1r,
                                                        const void* __restrict__ bn2r,
                                                        float* __restrict__ dst,
                                                        const int* __restrict__ flag) {
    int f = *flag;
    int idx = blockIdx.x * 256 + threadIdx.x;
    if (idx >= 41 * 128) return;
    int set = idx >> 7;
    int o = idx & 127;
    const void* bn; int bb = 0;
    if (set == 0) bn = bn1_0;
    else if (set == 1) bn = bn2_0;
    else if (set == 2) bn = bnd_0;
    else if (set < 22) { bn = bn1r; bb = (set - 3) * 512; }
    else { bn = bn2r; bb = (set - 22) * 512; }
    float s = ldin(bn, bb + o, f), b = ldin(bn, bb + 128 + o, f);
    float mu = ldin(bn, bb + 256 + o, f), v = ldin(bn, bb + 384 + o, f);
    float inv = s * rsqrtf(v + 1e-5f);
    dst[idx] = b - mu * inv;
}

// ---------------------------------------------------------------- generic implicit-GEMM conv (R7 structure)
// Used only for the two cheap x0 convs (K=32 / K=288).
__global__ __launch_bounds__(256) void conv_gemm(const u16* __restrict__ A,
                                                 const u16* __restrict__ W,
                                                 const float* __restrict__ bias,
                                                 u16* __restrict__ out,
                                                 int clog2, int nslab, int K,
                                                 int relu) {
    __shared__ u16 As[2][128 * 32];
    __shared__ u16 Bs[2][64 * 32];
    int tid = threadIdx.x;
    int m0 = blockIdx.x * 128;
    int n0 = blockIdx.y * 64;
    int Cin = 1 << clog2;

    int r0 = tid >> 2;
    int q8 = (tid & 3) * 8;
    int arow0 = pbase(m0 + r0, clog2) + q8;
    int arow1 = pbase(m0 + r0 + 64, clog2) + q8;
    int brow0 = (n0 + r0) * K + q8;
    int l8 = tid * 8;

    f32x4 acc[4][2];
    #pragma unroll
    for (int i = 0; i < 4; ++i)
        #pragma unroll
        for (int j = 0; j < 2; ++j)
            acc[i][j] = (f32x4){0.f, 0.f, 0.f, 0.f};

    int wid = tid >> 6;
    int wm = (wid >> 1) * 64;
    int wn = (wid & 1) * 32;
    int lane = tid & 63;
    int lr = lane & 15;
    int lq = lane >> 4;

    int nk = K >> 5;
    auto stage = [&](int buf, int kt) {
        int sl = kt >> clog2;
        int win = kt & (Cin - 1);
        int soff = 0;
        if (nslab == 9) {
            int d3 = sl / 3;
            soff = (((d3 - 1) * SPW + (sl - d3 * 3 - 1))) << clog2;
        }
        glds16(A + arow0 + soff + win, &As[buf][l8]);
        glds16(A + arow1 + soff + win, &As[buf][2048 + l8]);
        glds16(W + brow0 + kt, &Bs[buf][l8]);
    };

    stage(0, 0);
    #pragma unroll 1
    for (int it = 0; it < nk; ++it) {
        __syncthreads();
        if (it + 1 < nk) stage((it + 1) & 1, (it + 1) << 5);
        const u16* as = As[it & 1];
        const u16* bs = Bs[it & 1];
        bf16x8 af[4], bfr[2];
        #pragma unroll
        for (int i = 0; i < 4; ++i)
            af[i] = *(const bf16x8*)&as[(wm + i * 16 + lr) * 32 + lq * 8];
        #pragma unroll
        for (int j = 0; j < 2; ++j)
            bfr[j] = *(const bf16x8*)&bs[(wn + j * 16 + lr) * 32 + lq * 8];
        #pragma unroll
        for (int i = 0; i < 4; ++i)
            #pragma unroll
            for (int j = 0; j < 2; ++j)
                acc[i][j] = __builtin_amdgcn_mfma_f32_16x16x32_bf16(af[i], bfr[j], acc[i][j], 0, 0, 0);
    }

    #pragma unroll
    for (int i = 0; i < 4; ++i) {
        #pragma unroll
        for (int r = 0; r < 4; ++r) {
            int ml = m0 + wm + i * 16 + lq * 4 + r;
            int ob = pbase(ml, 7);
            #pragma unroll
            for (int j = 0; j < 2; ++j) {
                int n = n0 + wn + j * 16 + lr;
                float v = acc[i][j][r] + bias[n];
                if (relu) v = fmaxf(v, 0.f);
                out[ob + n] = f2b(v);
            }
        }
    }
}

// ---------------------------------------------------------------- chain conv (dil=1, 128ch in, 128ch out, K=1152)
// v9: v8 + FULL unroll of the 18-iter K-loop + explicit B register
// double-buffer. R12 lesson: time scales with per-iter WORK (barrier tax was
// only ~6%); with `unroll 1` the compiler cannot hoist the per-iter B global
// loads (2x ~250cyc L2 latency on the critical path) nor fold the runtime
// sl/3 address math (VALUBusy 17%). Full unroll makes every stage offset and
// B offset a compile-time constant and lets the scheduler move loads across
// iterations; bcur/bnxt issues B(it36+1) BEFORE the MFMAs of it36 so its L2
// latency hides under compute. Tile/swizzle/LDS/grid identical to v8.
__global__ __launch_bounds__(256, 4) void chain_conv(const u16* __restrict__ A,
                                                     const u16* __restrict__ W,   // frag-ordered [2][36][2][2][512]
                                                     const float* __restrict__ bias,
                                                     const u16* __restrict__ idn,
                                                     u16* __restrict__ out,
                                                     int relu) {
    __shared__ u16 As[2][2][128 * 32];   // [buf][k-half][row*32] = 32 KB
    int tid = threadIdx.x;
    int wg = blockIdx.x;
    int mt = (wg & 7) * 108 + (wg >> 3);   // bijective: 864 = 8*108; 108 mt = 2 images per XCD
    int m0 = mt * 128;

    int r0 = tid >> 2;
    int c8 = ((tid & 3) ^ (r0 & 3)) * 8;   // pre-swizzled logical chunk for this lane
    int pbq[2];
    #pragma unroll
    for (int q = 0; q < 2; ++q) {
        int p = m0 + r0 + q * 64;
        int b = p / HW6912;
        int rem = p - b * HW6912;
        int y = rem / IMW;
        int x = rem - y * IMW;
        pbq[q] = ((b * SPH + y + 1) * SPW + (x + 1)) * 128 + c8;
    }
    int l8 = tid * 8;

    f32x4 acc[4][4];
    #pragma unroll
    for (int i = 0; i < 4; ++i)
        #pragma unroll
        for (int jj = 0; jj < 4; ++jj)
            acc[i][jj] = (f32x4){0.f, 0.f, 0.f, 0.f};

    int wid = tid >> 6;
    int wm = (wid >> 1) * 64;
    int wn2 = wid & 1;                 // n-half: 64 cols
    int lane = tid & 63;
    int lr = lane & 15;
    int lq = lane >> 4;
    int rchunk = (lq ^ (lr & 3)) * 8;  // swizzled read chunk (row&3 == lr&3)

    // fragment-ordered W base: fragments at + it36*2048 + jj*512
    const u16* wv = W + wn2 * 73728 + lane * 8;

    auto stageh = [&](int buf, int it36) {   // it36 compile-time under full unroll
        int kt = it36 << 5;
        int sl = kt >> 7;           // tap 0..8
        int win = kt & 127;
        int d3 = sl / 3;
        int soff = ((d3 - 1) * SPW + (sl - d3 * 3 - 1)) * 128;
        glds16(A + pbq[0] + soff + win, &As[buf][it36 & 1][l8]);
        glds16(A + pbq[1] + soff + win, &As[buf][it36 & 1][2048 + l8]);
    };

    bf16x8 bcur[4], bnxt[4];
    #pragma unroll
    for (int jj = 0; jj < 4; ++jj)
        bcur[jj] = *(const bf16x8*)(wv + jj * 512);

    stageh(0, 0);
    stageh(0, 1);
    #pragma unroll
    for (int it = 0; it < 18; ++it) {
        __syncthreads();
        if (it + 1 < 18) {
            stageh((it + 1) & 1, (it + 1) * 2);
            stageh((it + 1) & 1, (it + 1) * 2 + 1);
        }
        #pragma unroll
        for (int kc = 0; kc < 2; ++kc) {
            int it36 = it * 2 + kc;
            if (it36 + 1 < 36) {
                #pragma unroll
                for (int jj = 0; jj < 4; ++jj)
                    bnxt[jj] = *(const bf16x8*)(wv + (it36 + 1) * 2048 + jj * 512);
            }
            const u16* as = As[it & 1][kc];
            bf16x8 af[4];
            #pragma unroll
            for (int i = 0; i < 4; ++i)
                af[i] = *(const bf16x8*)&as[(wm + i * 16 + lr) * 32 + rchunk];
            #pragma unroll
            for (int i = 0; i < 4; ++i)
                #pragma unroll
                for (int jj = 0; jj < 4; ++jj)
                    acc[i][jj] = __builtin_amdgcn_mfma_f32_16x16x32_bf16(af[i], bcur[jj], acc[i][jj], 0, 0, 0);
            if (it36 + 1 < 36) {
                #pragma unroll
                for (int jj = 0; jj < 4; ++jj)
                    bcur[jj] = bnxt[jj];
            }
        }
    }

    #pragma unroll
    for (int i = 0; i < 4; ++i) {
        #pragma unroll
        for (int r = 0; r < 4; ++r) {
            int ml = m0 + wm + i * 16 + lq * 4 + r;
            int ob = pbase(ml, 7);
            #pragma unroll
            for (int jj = 0; jj < 4; ++jj) {
                int n = wn2 * 64 + jj * 16 + lr;
                float v = acc[i][jj][r] + bias[n];
                if (idn) v += b2f(idn[ob + n]);
                if (relu) v = fmaxf(v, 0.f);
                out[ob + n] = f2b(v);
            }
        }
    }
}

// ---------------------------------------------------------------- offset conv (dilated, reads h1s with explicit zero-pad)
// v3: XCD-locality swizzle (27 mt per XCD, 8 nt-tiles adjacent).
__global__ __launch_bounds__(256, 8) void off_conv(const u16* __restrict__ A,   // h1s
                                                   const u16* __restrict__ W,   // frag-ordered [nt][it][w2][j][64*8]
                                                   u16* __restrict__ out,       // [m_local][468]
                                                   int dil, int m_base) {
    __shared__ u16 As[2][128 * 32];
    int tid = threadIdx.x;
    int wg = blockIdx.x;
    int sw = (wg & 7) * 216 + (wg >> 3);   // bijective: 1728 = 8*216
    int mt = sw >> 3, nt = sw & 7;
    int m0 = mt * 128, n0 = nt * 64;

    int r0 = tid >> 2;
    int q8 = (tid & 3) * 8;
    int pb2[2], py[2], px[2];
    #pragma unroll
    for (int q = 0; q < 2; ++q) {
        int p = m_base + m0 + r0 + q * 64;
        int b = p / HW6912;
        int rem = p - b * HW6912;
        pb2[q] = b;
        py[q] = rem / IMW;
        px[q] = rem - py[q] * IMW;
    }
    int l8 = tid * 8;

    f32x4 acc[4][2];
    #pragma unroll
    for (int i = 0; i < 4; ++i) {
        acc[i][0] = (f32x4){0.f, 0.f, 0.f, 0.f};
        acc[i][1] = (f32x4){0.f, 0.f, 0.f, 0.f};
    }

    int wid = tid >> 6;
    int wm = (wid >> 1) * 64;
    int wn = (wid & 1) * 32;
    int lane = tid & 63;
    int lr = lane & 15;
    int lq = lane >> 4;

    // fragment-ordered W base for this wave: + it*2048 + j*512 per fragment
    const u16* wv = W + nt * 73728 + (wid & 1) * 1024 + lane * 8;

    auto stage = [&](int buf, int kt) {
        int sl = kt >> 7;
        int win = kt & 127;
        int d3 = sl / 3;
        int dy = (d3 - 1) * dil, dx = (sl - d3 * 3 - 1) * dil;
        #pragma unroll
        for (int q = 0; q < 2; ++q) {
            int y2 = py[q] + dy, x2 = px[q] + dx;
            uint4 v = make_uint4(0u, 0u, 0u, 0u);
            if (y2 >= 0 && y2 < IMH && x2 >= 0 && x2 < IMW)
                v = *(const uint4*)(A + ((pb2[q] * SPH + y2 + 1) * SPW + x2 + 1) * 128 + win + q8);
            *(uint4*)&As[buf][q * 2048 + l8] = v;
        }
    };

    stage(0, 0);
    #pragma unroll 1
    for (int it = 0; it < 36; ++it) {
        __syncthreads();
        if (it + 1 < 36) stage((it + 1) & 1, (it + 1) << 5);
        const u16* as = As[it & 1];
        bf16x8 af[4], bfr[2];
        #pragma unroll
        for (int i = 0; i < 4; ++i)
            af[i] = *(const bf16x8*)&as[(wm + i * 16 + lr) * 32 + lq * 8];
        bfr[0] = *(const bf16x8*)(wv + it * 2048);
        bfr[1] = *(const bf16x8*)(wv + it * 2048 + 512);
        #pragma unroll
        for (int i = 0; i < 4; ++i)
            #pragma unroll
            for (int j = 0; j < 2; ++j)
                acc[i][j] = __builtin_amdgcn_mfma_f32_16x16x32_bf16(af[i], bfr[j], acc[i][j], 0, 0, 0);
    }

    #pragma unroll
    for (int i = 0; i < 4; ++i) {
        #pragma unroll
        for (int r = 0; r < 4; ++r) {
            int ml = m0 + wm + i * 16 + lq * 4 + r;
            int ob = ml * 468;
            #pragma unroll
            for (int j = 0; j < 2; ++j) {
                int n = n0 + wn + j * 16 + lr;
                if (n < 468) out[ob + n] = f2b(acc[i][j][r]);
            }
        }
    }
}

// ---------------------------------------------------------------- deformable conv
template <int F>
__device__ __forceinline__ float dsamp2(const void* sup, int base, int yi, int xi) {
    bool ok = (yi >= 0) & (yi < IMH) & (xi >= 0) & (xi < IMW);
    int yc = yi < 0 ? 0 : (yi > IMH - 1 ? IMH - 1 : yi);
    int xc = xi < 0 ? 0 : (xi > IMW - 1 ? IMW - 1 : xi);
    float v = F ? ((const float*)sup)[base + yc * IMW + xc]
                : b2f(((const u16*)sup)[base + yc * IMW + xc]);
    return ok ? v : 0.f;
}

template <int F>
__device__ __forceinline__ void deform_body(const void* __restrict__ sup,
                                            const u16* __restrict__ oc,
                                            const float* __restrict__ wsm,
                                            f32x4 acc[7],
                                            int c0, int c1, int b, int y, int x, int dil) {
    #pragma unroll 1
    for (int c = c0; c < c1; ++c) {
        int ibase = (b * CIN + c) * HW6912;
        #pragma unroll
        for (int t = 0; t < 9; ++t) {
            u32 pr = *(const u32*)(oc + c * 18 + t * 2);
            float dy = b2f((u16)(pr & 0xffffu));
            float dx = b2f((u16)(pr >> 16));
            float py = (float)(y + (t / 3 - 1) * dil) + dy;
            float px = (float)(x + (t % 3 - 1) * dil) + dx;
            float y0f = floorf(py), x0f = floorf(px);
            float ly = py - y0f, lx = px - x0f;
            int y0 = (int)y0f, x0 = (int)x0f;
            float v00 = dsamp2<F>(sup, ibase, y0, x0);
            float v01 = dsamp2<F>(sup, ibase, y0, x0 + 1);
            float v10 = dsamp2<F>(sup, ibase, y0 + 1, x0);
            float v11 = dsamp2<F>(sup, ibase, y0 + 1, x0 + 1);
            float val = (v00 * (1.f - lx) + v01 * lx) * (1.f - ly)
                      + (v10 * (1.f - lx) + v11 * lx) * ly;
            const float4* wr = (const float4*)&wsm[(c * 9 + t) * 28];
            #pragma unroll
            for (int u = 0; u < 7; ++u) {
                float4 w4 = wr[u];
                acc[u][0] = fmaf(val, w4.x, acc[u][0]);
                acc[u][1] = fmaf(val, w4.y, acc[u][1]);
                acc[u][2] = fmaf(val, w4.z, acc[u][2]);
                acc[u][3] = fmaf(val, w4.w, acc[u][3]);
            }
        }
    }
}

// v4 (R10-proven): 32px x 8cg, 864 blocks, XCD swizzle, no atomics;
// shfl_xor(32) pair-reduce + red[4][32][27]; coalesced wsm from prep_dw.
__global__ __launch_bounds__(256) void deform_kernel(const void* __restrict__ sup,
                                                     const u16* __restrict__ offb,
                                                     const float* __restrict__ wsp,
                                                     float* __restrict__ accws,
                                                     int dil, int first, int m_base,
                                                     const int* __restrict__ flag) {
    int f = *flag;
    __shared__ alignas(16) float wsm[26 * 9 * 28];
    __shared__ float red[4 * 32 * 27];
    int tid = threadIdx.x;
    int bid = blockIdx.x;
    int sw = (bid & 7) * 108 + (bid >> 3);   // bijective: 864 = 8*108
    for (int i = tid; i < 1638; i += 256)
        ((float4*)wsm)[i] = ((const float4*)wsp)[i];
    __syncthreads();

    int px = tid & 31;
    int cg = tid >> 5;                 // 0..7
    int c0 = (cg * 26) >> 3;
    int c1 = ((cg + 1) * 26) >> 3;
    int ml = sw * 32 + px;
    int m = m_base + ml;
    int b = m / HW6912;
    int p = m - b * HW6912;
    int y = p / IMW;
    int x = p - y * IMW;

    f32x4 acc[7];
    #pragma unroll
    for (int u = 0; u < 7; ++u) acc[u] = (f32x4){0.f, 0.f, 0.f, 0.f};

    const u16* oc = offb + (size_t)ml * 468;
    if (f) deform_body<1>(sup, oc, wsm, acc, c0, c1, b, y, x, dil);
    else   deform_body<0>(sup, oc, wsm, acc, c0, c1, b, y, x, dil);

    // in-wave pair-reduce: lane l <-> l^32 (same px, cg pair 2w/2w+1)
    #pragma unroll
    for (int u = 0; u < 7; ++u)
        #pragma unroll
        for (int k2 = 0; k2 < 4; ++k2) {
            float v = acc[u][k2];
            acc[u][k2] = v + __shfl_xor(v, 32);
        }

    int w = tid >> 6;                  // wave 0..3
    if (!(tid & 32)) {                 // lanes 0-31 of each wave hold the pair sum
        float* mr = red + (w * 32 + px) * 27;
        #pragma unroll
        for (int u = 0; u < 7; ++u)
            #pragma unroll
            for (int k2 = 0; k2 < 4; ++k2) {
                int o = u * 4 + k2;
                if (o < 26) mr[o] = acc[u][k2];
            }
    }
    __syncthreads();

    int base_m = m_base + sw * 32;
    for (int v = tid; v < 32 * 26; v += 256) {
        int ppx = v / 26;
        int o = v - ppx * 26;
        float s = red[(0 * 32 + ppx) * 27 + o] + red[(1 * 32 + ppx) * 27 + o]
                + red[(2 * 32 + ppx) * 27 + o] + red[(3 * 32 + ppx) * 27 + o];
        size_t ai = (size_t)(base_m + ppx) * 32 + o;
        if (first) accws[ai] = s;
        else       accws[ai] += s;
    }
}

// ---------------------------------------------------------------- finalize
__global__ __launch_bounds__(256) void finalize_kernel(const float* __restrict__ accws,
                                                       void* __restrict__ out,
                                                       const int* __restrict__ flag) {
    int f = *flag;
    int q = blockIdx.x * 256 + threadIdx.x;
    int b = q / (CIN * HW6912);
    int r = q - b * (CIN * HW6912);
    int o = r / HW6912;
    int p = r - o * HW6912;
    float v = accws[(size_t)(b * HW6912 + p) * 32 + o] * 0.2f;
    if (f) ((float*)out)[q] = v;
    else   ((u16*)out)[q] = f2b(v);
}

// ---------------------------------------------------------------- host
extern "C" void kernel_launch(void* const* d_in, const int* in_sizes, int n_in,
                              void* d_out, int out_size, void* d_ws, size_t ws_size,
                              hipStream_t stream) {
    (void)in_sizes; (void)n_in; (void)out_size;
    const void* ref_x    = d_in[0];
    const void* sup_x    = d_in[1];
    const void* w1_0     = d_in[2];
    const void* w2_0     = d_in[3];
    const void* wd_0     = d_in[4];
    const void* bn1_0    = d_in[5];
    const void* bn2_0    = d_in[6];
    const void* bnd_0    = d_in[7];
    const void* w1_rest  = d_in[8];
    const void* w2_rest  = d_in[9];
    const void* bn1_rest = d_in[10];
    const void* bn2_rest = d_in[11];
    const void* offset_w = d_in[12];
    const void* deform_w = d_in[13];

    // workspace layout (bytes)
    size_t o_x0    = 0;                          // 16*98*74*32*2   =  7,426,048
    size_t o_h0    = o_x0 + 7426048;             // 16*98*74*128*2  = 29,704,192 (offb aliases)
    size_t o_h1s   = o_h0 + 29704192;            // 29,704,192
    size_t o_acc   = o_h1s + 29704192;           // 14,155,776
    size_t o_wrest = o_acc + 14155776;           // 11,206,656
    size_t o_w20   = o_wrest + 11206656;         //    294,912
    size_t o_w10   = o_w20 + 294912;             //     73,728
    size_t o_wd    = o_w10 + 73728;              //      8,192
    size_t o_woff  = o_wd + 8192;                //  5,898,240
    size_t o_bias  = o_woff + 5898240;           //     20,992
    size_t o_wsall = o_bias + 20992;             //    131,072 (5*6552 floats)
    size_t o_flag  = o_wsall + 131072;           //         64
    size_t o_end   = o_flag + 64;                // 98,624,128
    if (ws_size < o_end) return;

    char* ws = (char*)d_ws;
    u16* x0    = (u16*)(ws + o_x0);
    u16* h0    = (u16*)(ws + o_h0);
    u16* offb  = (u16*)(ws + o_h0);      // alias: h0 dead once the chain finishes
    u16* h1s   = (u16*)(ws + o_h1s);
    float* accb = (float*)(ws + o_acc);
    u16* Wr    = (u16*)(ws + o_wrest);
    u16* W20   = (u16*)(ws + o_w20);
    u16* W10   = (u16*)(ws + o_w10);
    u16* Wd    = (u16*)(ws + o_wd);
    u16* Woff  = (u16*)(ws + o_woff);
    float* biasb = (float*)(ws + o_bias);
    float* wsall = (float*)(ws + o_wsall);
    int* flagp = (int*)(ws + o_flag);

    dim3 blk(256);

    probe_kernel<<<1, 64, 0, stream>>>(bn1_0, flagp);
    // zero x0 + h0 + h1s (padding halos must be zero)
    zero_ws_kernel<<<2048, blk, 0, stream>>>((uint4*)ws, (int)((7426048 + 2 * 29704192) / 16));
    fill_x0_kernel<<<432, blk, 0, stream>>>(ref_x, sup_x, x0, flagp);
    prep_rest_kernel<<<21888, blk, 0, stream>>>(w1_rest, w2_rest, bn1_rest, bn2_rest, Wr, flagp);
    prep_b0_kernel<<<736, blk, 0, stream>>>(w1_0, w2_0, wd_0, bn1_0, bn2_0, bnd_0, W20, W10, Wd, flagp);
    prep_off_kernel<<<11520, blk, 0, stream>>>(offset_w, Woff, flagp);
    prep_dw_kernel<<<128, blk, 0, stream>>>(deform_w, wsall, flagp);
    prep_bias_kernel<<<21, blk, 0, stream>>>(bn1_0, bn2_0, bnd_0, bn1_rest, bn2_rest, biasb, flagp);

    // block0: downsample (1x1 conv + BN) x0 -> h1s ; conv1 x0 -> h0
    conv_gemm<<<dim3(864, 2), blk, 0, stream>>>(x0, Wd, biasb + 2 * 128, h1s, 5, 1, 32, 0);
    conv_gemm<<<dim3(864, 2), blk, 0, stream>>>(x0, W10, biasb + 0 * 128, h0, 5, 9, 288, 1);
    // block0: conv2 + BN + idn(h1s) + relu -> h1s
    chain_conv<<<864, blk, 0, stream>>>(h0, W20, biasb + 1 * 128, h1s, h1s, 1);

    for (int t = 0; t < 19; ++t) {
        const u16* wa = Wr + (size_t)t * 147456;
        const u16* wb = Wr + (size_t)(19 + t) * 147456;
        chain_conv<<<864, blk, 0, stream>>>(h1s, wa, biasb + (3 + t) * 128, nullptr, h0, 1);
        chain_conv<<<864, blk, 0, stream>>>(h0, wb, biasb + (22 + t) * 128, h1s, h1s, 1);
    }

    // 5 dilation branches, chunked over 4 batches (offb aliases h0)
    const int dils[5] = {3, 6, 12, 18, 24};
    for (int i = 0; i < 5; ++i) {
        for (int cb = 0; cb < 4; ++cb) {
            int mb = cb * 27648;
            off_conv<<<1728, blk, 0, stream>>>(h1s, Woff + (size_t)i * 589824, offb, dils[i], mb);
            deform_kernel<<<864, blk, 0, stream>>>(sup_x, offb, wsall + (size_t)i * 6552,
                                                   accb, dils[i], (i == 0) ? 1 : 0, mb, flagp);
        }
    }
    finalize_kernel<<<11232, blk, 0, stream>>>(accb, d_out, flagp);
}